// Round 9
// baseline (1835.042 us; speedup 1.0000x reference)
//
#include <hip/hip_runtime.h>
#include <cstddef>

#define NE 16384
#define NN 4096
#define BG 16
#define NT 16      // nodes per conv tile
#define ACH 8      // a-chunk size (8 chunks of 8 = 64), double-buffered

__device__ __forceinline__ float lrelu(float v){ return v >= 0.f ? v : 0.01f*v; }
__device__ __forceinline__ float sigm(float v){ return 1.f/(1.f + expf(-v)); }
__device__ __forceinline__ void fma4(float4& a, float s, const float4& w){
    a.x += s*w.x; a.y += s*w.y; a.z += s*w.z; a.w += s*w.w;
}

// ---------------- setup: W8T, h0, he, deg(dst), cnt(src) ----------------
__global__ __launch_bounds__(256) void setup_kernel(
    const float* __restrict__ x, const float* __restrict__ ea,
    const int* __restrict__ ei,
    const float* __restrict__ W0, const float* __restrict__ b0,
    const float* __restrict__ We1, const float* __restrict__ be1,
    const float* __restrict__ Wih, const float* __restrict__ Whh,
    float* __restrict__ W8T,
    float* __restrict__ h, float* __restrict__ he,
    int* __restrict__ deg, int* __restrict__ cnt)
{
    int t = blockIdx.x*256 + threadIdx.x;   // grid: 4096x256 = 1048576
    {   // he: [E,64]  lrelu(edge_attr @ We1 + be1)
        int e = t >> 6, f = t & 63;
        float v = be1[f];
        #pragma unroll
        for (int d = 0; d < 4; ++d) v += ea[e*4+d]*We1[d*64+f];
        he[t] = lrelu(v);
    }
    if (t < NN*64) {    // h0 = lrelu(x @ W0 + b0)
        int n = t >> 6, f = t & 63;
        float v = b0[f];
        #pragma unroll
        for (int d = 0; d < 3; ++d) v += x[n*3+d]*W0[d*64+f];
        h[t] = lrelu(v);
    }
    if (t < 32768) {    // W8T[k][g][8] = {Wih_r,Wih_z,Wih_n,Whh_r,Whh_z,Whh_n,0,0}
        int k = t >> 9, g = (t >> 3) & 63, j = t & 7;
        float v = 0.f;
        if (j < 3)      v = Wih[(j*64+g)*64 + k];
        else if (j < 6) v = Whh[((j-3)*64+g)*64 + k];
        W8T[t] = v;
    }
    if (t < NE) {
        atomicAdd(&deg[ei[NE + t]], 1);   // in-degree (dst) for mean aggr
        atomicAdd(&cnt[ei[t]], 1);        // out-degree (src) for edge sort
    }
}

// ---------------- exclusive scan of cnt[4096] -> offs[4097] (1 block) ----------------
__global__ __launch_bounds__(256) void scan_kernel(const int* __restrict__ cnt,
                                                   int* __restrict__ offs)
{
    __shared__ int ps[256];
    int t = threadIdx.x;
    int base = t*16;
    int loc[16];
    int s = 0;
    #pragma unroll
    for (int i = 0; i < 16; ++i) { loc[i] = s; s += cnt[base+i]; }
    ps[t] = s; __syncthreads();
    for (int off = 1; off < 256; off <<= 1) {
        int v = 0;
        if (t >= off) v = ps[t-off];
        __syncthreads();
        if (t >= off) ps[t] += v;
        __syncthreads();
    }
    int pre = (t == 0) ? 0 : ps[t-1];
    #pragma unroll
    for (int i = 0; i < 16; ++i) offs[base+i] = pre + loc[i];
    if (t == 255) offs[NN] = pre + s;
}

// ---------------- scatter: build src-sorted edge arrays ----------------
__global__ __launch_bounds__(256) void scatter_kernel(
    const int* __restrict__ ei, const int* __restrict__ offs,
    int* __restrict__ cnt,  // consumed as cursor via atomicSub
    int* __restrict__ srcs, int* __restrict__ dsts, int* __restrict__ perm)
{
    int e = blockIdx.x*256 + threadIdx.x;
    if (e >= NE) return;
    int s = ei[e], d = ei[NE + e];
    int old = atomicSub(&cnt[s], 1);
    int pos = offs[s] + old - 1;
    srcs[pos] = s; dsts[pos] = d; perm[pos] = e;
}

// ---------------- gather he rows into src-sorted order ----------------
__global__ __launch_bounds__(256) void reorder_kernel(
    const float* __restrict__ he, const int* __restrict__ perm,
    float* __restrict__ he_srt)
{
    int t = blockIdx.x*256 + threadIdx.x;   // 4096 x 256 = NE*64
    he_srt[t] = he[(size_t)perm[t>>6]*64 + (t & 63)];
}

// ---------------- inv_deg + per-graph node ranges ----------------
__global__ __launch_bounds__(256) void inv_range_kernel(
    const int* __restrict__ deg, const int* __restrict__ batch,
    float* __restrict__ inv_deg, int* __restrict__ gstart, int* __restrict__ gend)
{
    int n = blockIdx.x*256 + threadIdx.x;   // 16 blocks -> 4096
    if (n >= NN) return;
    inv_deg[n] = 1.f / fmaxf((float)deg[n], 1.f);
    int b  = batch[n];
    int bp = (n == 0)    ? -1 : batch[n-1];
    int bn = (n == NN-1) ? BG : batch[n+1];
    for (int g = bp+1; g <= b; ++g) gstart[g] = n;
    for (int g = b;   g <  bn; ++g) gend[g]   = n+1;
    if (n == 0)    for (int g = 0;   g < b;  ++g) gend[g]   = 0;
    if (n == NN-1) for (int g = b+1; g < BG; ++g) gstart[g] = NN;
}

// ---------------- fused conv: producer/consumer, h in NAMED registers ----------------
// R5 structure + h-in-registers done without any local array (R7/R8 post-mortem:
// `float hr[32]` was runtime-indexed after the compiler declined the big unroll
// -> localMem scratch, 114 MB writes, VGPR pinned at cap). Here the h half-row
// lives in 8 NAMED float4s and the 64-i FMA chain is macro-expanded with static
// component accesses only. Producer thread = (a-wave, 1 node, 16 f):
// 16 ds_read_b128/thread/chunk vs R5's 64 -> producer LDS 4096 -> 1024 b128/tile.
// (1024,2): VGPR cap ~128 (R2/R8 evidence: cap ~= 256/min_waves).
__global__ __launch_bounds__(1024, 2) void conv_kernel(
    const float* __restrict__ h, const float* __restrict__ We2,
    const float* __restrict__ be2, const float* __restrict__ he_srt,
    const int* __restrict__ offs, const int* __restrict__ srcs,
    const int* __restrict__ dsts, float* __restrict__ agg)
{
    __shared__ float hs[NT][68];           // h tile, row-padded    4.3 KB
    __shared__ float Tb[NT][64];           // 4 KB
    __shared__ float Tc[2][ACH][NT][68];   // dbuf, f-padded       69.6 KB
    __shared__ float he_s[2][128][ACH];    // dbuf                  8 KB
    int t  = threadIdx.x;
    int n0 = blockIdx.x * NT;

    if (t < 256) {   // stage h tile (16 x 64)
        int n = t >> 4, j = (t & 15) * 4;
        *(float4*)&hs[n][j] = *(const float4*)&h[(size_t)(n0+n)*64 + j];
    }
    int ebase = offs[n0];
    int ecnt  = offs[n0+NT] - ebase;
    int eend  = ebase + ecnt;
    __syncthreads();

    // producer mapping (t < 512): wave = a', lane = (node, f16-block)
    int aT = t >> 6;             // 0..7   a' within chunk
    int nT = (t >> 2) & 15;      // node 0..15
    int fb = (t & 3) * 16;       // f-block of 16
    // consumer mapping + persistent state (t >= 512): (slot, f4)  [R5 proven]
    int ct   = t - 512;
    int slot = ct >> 4;          // 0..31 edge slots
    int f4   = (ct & 15) * 4;    // 4 output features per thread
    int nl0=-1,dt0=0,nl1=-1,dt1=0,nl2=-1,dt2=0,nl3=-1,dt3=0;
    float4 m0={0,0,0,0},m1={0,0,0,0},m2={0,0,0,0},m3={0,0,0,0};
    if (t >= 512) {
        if (slot      < ecnt) { nl0 = srcs[ebase+slot]    - n0; dt0 = dsts[ebase+slot];    }
        if (slot + 32 < ecnt) { nl1 = srcs[ebase+slot+32] - n0; dt1 = dsts[ebase+slot+32]; }
        if (slot + 64 < ecnt) { nl2 = srcs[ebase+slot+64] - n0; dt2 = dsts[ebase+slot+64]; }
        if (slot + 96 < ecnt) { nl3 = srcs[ebase+slot+96] - n0; dt3 = dsts[ebase+slot+96]; }
    }

#define EDGE_ACC(mj, nlj, row, buf_) \
    if (nlj >= 0) { \
        float4 hA = *(const float4*)&he_s[buf_][row][0]; \
        float4 hB = *(const float4*)&he_s[buf_][row][4]; \
        float he8[8] = {hA.x,hA.y,hA.z,hA.w,hB.x,hB.y,hB.z,hB.w}; \
        _Pragma("unroll") \
        for (int a_ = 0; a_ < 8; ++a_) { \
            float4 tv = *(const float4*)&Tc[buf_][a_][nlj][f4]; \
            fma4(mj, he8[a_], tv); \
        } \
    }

#define CONSUME(cm) { \
    int buf_ = (cm) & 1; \
    EDGE_ACC(m0, nl0, (slot),      buf_) \
    EDGE_ACC(m1, nl1, (slot+32),   buf_) \
    EDGE_ACC(m2, nl2, (slot+64),   buf_) \
    EDGE_ACC(m3, nl3, (slot+96),   buf_) \
    for (int e = ebase + 128 + slot; e < eend; e += 32) { \
        int nl = srcs[e] - n0, dtv = dsts[e]; \
        const float* hep = he_srt + (size_t)e*64 + (cm)*ACH; \
        float4 pm = {0,0,0,0}; \
        _Pragma("unroll") \
        for (int a_ = 0; a_ < 8; ++a_) { \
            float hv = hep[a_]; \
            float4 tv = *(const float4*)&Tc[buf_][a_][nl][f4]; \
            fma4(pm, hv, tv); \
        } \
        if ((cm) == 0) { \
            float4 b = *(const float4*)&Tb[nl][f4]; \
            pm.x += b.x; pm.y += b.y; pm.z += b.z; pm.w += b.w; \
        } \
        float* ap = agg + (size_t)dtv*64 + f4; \
        atomicAdd(ap+0, pm.x); atomicAdd(ap+1, pm.y); \
        atomicAdd(ap+2, pm.z); atomicAdd(ap+3, pm.w); \
    } \
}

// producer inner step: one i (scalar h component) against 16 f
#define PW(ioff, hv) { \
        const float* wi = Wp + (size_t)(ioff)*64; \
        float4 w0 = *(const float4*)(wi); \
        float4 w1 = *(const float4*)(wi + 4); \
        float4 w2 = *(const float4*)(wi + 8); \
        float4 w3 = *(const float4*)(wi + 12); \
        fma4(a0, hv, w0); fma4(a1, hv, w1); \
        fma4(a2, hv, w2); fma4(a3, hv, w3); }
#define PH(hreg, ib) PW(ib, hreg.x) PW((ib)+1, hreg.y) PW((ib)+2, hreg.z) PW((ib)+3, hreg.w)

    for (int c = 0; c < 8; ++c) {
        if (t < 512) {
            // ---- producer: T chunk c -> Tc[c&1]; h in named registers ----
            const float* Wp = We2 + (size_t)(c*ACH + aT)*4096 + fb;
            float4 a0={0,0,0,0}, a1={0,0,0,0}, a2={0,0,0,0}, a3={0,0,0,0};
            {
                float4 h0 = *(const float4*)&hs[nT][0];
                float4 h1 = *(const float4*)&hs[nT][4];
                float4 h2 = *(const float4*)&hs[nT][8];
                float4 h3 = *(const float4*)&hs[nT][12];
                float4 h4 = *(const float4*)&hs[nT][16];
                float4 h5 = *(const float4*)&hs[nT][20];
                float4 h6 = *(const float4*)&hs[nT][24];
                float4 h7 = *(const float4*)&hs[nT][28];
                PH(h0, 0)  PH(h1, 4)  PH(h2, 8)  PH(h3, 12)
                PH(h4, 16) PH(h5, 20) PH(h6, 24) PH(h7, 28)
                h0 = *(const float4*)&hs[nT][32];
                h1 = *(const float4*)&hs[nT][36];
                h2 = *(const float4*)&hs[nT][40];
                h3 = *(const float4*)&hs[nT][44];
                h4 = *(const float4*)&hs[nT][48];
                h5 = *(const float4*)&hs[nT][52];
                h6 = *(const float4*)&hs[nT][56];
                h7 = *(const float4*)&hs[nT][60];
                PH(h0, 32) PH(h1, 36) PH(h2, 40) PH(h3, 44)
                PH(h4, 48) PH(h5, 52) PH(h6, 56) PH(h7, 60)
            }
            int buf = c & 1;
            *(float4*)&Tc[buf][aT][nT][fb]      = a0;
            *(float4*)&Tc[buf][aT][nT][fb + 4]  = a1;
            *(float4*)&Tc[buf][aT][nT][fb + 8]  = a2;
            *(float4*)&Tc[buf][aT][nT][fb + 12] = a3;
        } else {
            {   // ---- consumer: stage he chunk c (consumed next phase) ----
                int le = ct >> 2, a2s = (ct & 3) * 2;
                if (ebase + le < NE)
                    *(float2*)&he_s[c&1][le][a2s] =
                        *(const float2*)&he_srt[(size_t)(ebase+le)*64 + c*ACH + a2s];
            }
            if (c == 0) {
                // Tb[n][f] = sum_i h[n,i]*be2[i*64+f]  (overlapped with chunk 0)
                int n = ct >> 5, fp = (ct & 31) * 2;
                float t0 = 0.f, t1 = 0.f;
                #pragma unroll 8
                for (int i = 0; i < 64; ++i) {
                    float hv = hs[n][i];
                    float2 b = *(const float2*)&be2[(size_t)i*64 + fp];
                    t0 += hv*b.x; t1 += hv*b.y;
                }
                Tb[n][fp]   = t0;
                Tb[n][fp+1] = t1;
            } else {
                CONSUME(c-1);
            }
        }
        __syncthreads();
    }
    if (t >= 512) {
        CONSUME(7);
        // ---- scatter: one atomic add per edge (msg + bias) ----
        if (nl0 >= 0) {
            float4 b = *(const float4*)&Tb[nl0][f4];
            float* ap = agg + (size_t)dt0*64 + f4;
            atomicAdd(ap+0, m0.x+b.x); atomicAdd(ap+1, m0.y+b.y);
            atomicAdd(ap+2, m0.z+b.z); atomicAdd(ap+3, m0.w+b.w);
        }
        if (nl1 >= 0) {
            float4 b = *(const float4*)&Tb[nl1][f4];
            float* ap = agg + (size_t)dt1*64 + f4;
            atomicAdd(ap+0, m1.x+b.x); atomicAdd(ap+1, m1.y+b.y);
            atomicAdd(ap+2, m1.z+b.z); atomicAdd(ap+3, m1.w+b.w);
        }
        if (nl2 >= 0) {
            float4 b = *(const float4*)&Tb[nl2][f4];
            float* ap = agg + (size_t)dt2*64 + f4;
            atomicAdd(ap+0, m2.x+b.x); atomicAdd(ap+1, m2.y+b.y);
            atomicAdd(ap+2, m2.z+b.z); atomicAdd(ap+3, m2.w+b.w);
        }
        if (nl3 >= 0) {
            float4 b = *(const float4*)&Tb[nl3][f4];
            float* ap = agg + (size_t)dt3*64 + f4;
            atomicAdd(ap+0, m3.x+b.x); atomicAdd(ap+1, m3.y+b.y);
            atomicAdd(ap+2, m3.z+b.z); atomicAdd(ap+3, m3.w+b.w);
        }
    }
#undef CONSUME
#undef EDGE_ACC
#undef PW
#undef PH
}

// ---------------- node kernel: m, gi, gh + GRU; thread = (node, gate-col) ----
__global__ __launch_bounds__(512) void node_kernel(
    const float* __restrict__ W8T, const float* __restrict__ root,
    const float* __restrict__ conv_b, const float* __restrict__ inv_deg,
    const float* __restrict__ bih, const float* __restrict__ bhh,
    float* __restrict__ h, float* __restrict__ agg)
{
    __shared__ float hs[8][64];
    __shared__ float ms[8][64];
    int t = threadIdx.x;
    int n = t >> 6, g = t & 63;
    int gn = blockIdx.x*8 + n;
    hs[n][g] = h[(size_t)gn*64 + g];
    __syncthreads();
    {   // m = lrelu(agg*inv_deg + h@root + conv_b)
        size_t ix = (size_t)gn*64 + g;
        float v = agg[ix]*inv_deg[gn] + conv_b[g];
        agg[ix] = 0.f;                     // ready for next iteration's conv
        #pragma unroll 8
        for (int k = 0; k < 64; ++k) v += hs[n][k]*root[k*64 + g];
        ms[n][g] = lrelu(v);
    }
    __syncthreads();

    float ir=0.f, iz=0.f, in_=0.f, hr=0.f, hz=0.f, hn=0.f;
    const float* Wp = W8T + (size_t)g*8;
    #pragma unroll 8
    for (int k = 0; k < 64; ++k) {
        float am = ms[n][k], ah = hs[n][k];
        float4 w0 = *(const float4*)(Wp + (size_t)k*512);
        float4 w1 = *(const float4*)(Wp + (size_t)k*512 + 4);
        ir  += am*w0.x; iz += am*w0.y; in_ += am*w0.z;
        hr  += ah*w0.w; hz += ah*w1.x; hn  += ah*w1.y;
    }
    float r  = sigm(ir + bih[g]      + hr + bhh[g]);
    float z  = sigm(iz + bih[64+g]   + hz + bhh[64+g]);
    float nn = tanhf(in_ + bih[128+g] + r*(hn + bhh[128+g]));
    h[(size_t)gn*64 + g] = (1.f - z)*nn + z*hs[n][g];
}

// ---------------- finale ----------------
__device__ __forceinline__ float q_val(const float* lbih, const float* lbhh, int g)
{
    float gi = lbih[g]     + lbhh[g];
    float gg = lbih[128+g] + lbhh[128+g];
    float go = lbih[192+g] + lbhh[192+g];
    return sigm(go)*tanhf(sigm(gi)*tanhf(gg));   // hl0=cl0=q_star0=0
}

__global__ __launch_bounds__(256) void e_kernel(
    const float* __restrict__ h, const float* __restrict__ lbih,
    const float* __restrict__ lbhh, float* __restrict__ e)
{
    __shared__ float qs[64];
    int t = threadIdx.x;
    if (t < 64) qs[t] = q_val(lbih, lbhh, t);
    __syncthreads();
    int w = t >> 6, f = t & 63;
    int n = blockIdx.x*4 + w;
    float p = h[(size_t)n*64 + f]*qs[f];
    #pragma unroll
    for (int off = 32; off; off >>= 1) p += __shfl_xor(p, off);
    if (f == 0) e[n] = p;
}

__global__ __launch_bounds__(1024) void pool_kernel(
    const float* __restrict__ h, float* __restrict__ e,
    const int* __restrict__ gstart, const int* __restrict__ gend,
    const float* __restrict__ lbih, const float* __restrict__ lbhh,
    const float* __restrict__ Wout, const float* __restrict__ bout,
    float* __restrict__ out)
{
    __shared__ float red[1024];
    __shared__ float rp[64];
    __shared__ float sval;
    int g = blockIdx.x, t = threadIdx.x;
    int s = gstart[g], en = gend[g];

    float mx = -1e30f;
    for (int n = s+t; n < en; n += 1024) mx = fmaxf(mx, e[n]);
    red[t] = mx; __syncthreads();
    for (int st = 512; st; st >>= 1) { if (t < st) red[t] = fmaxf(red[t], red[t+st]); __syncthreads(); }
    if (t == 0) sval = red[0];
    __syncthreads();
    float lmx = sval;
    __syncthreads();

    float sm = 0.f;
    for (int n = s+t; n < en; n += 1024) { float a = expf(e[n]-lmx); e[n] = a; sm += a; }
    red[t] = sm; __syncthreads();
    for (int st = 512; st; st >>= 1) { if (t < st) red[t] += red[t+st]; __syncthreads(); }
    if (t == 0) sval = (red[0] > 0.f) ? 1.f/red[0] : 0.f;
    __syncthreads();
    float inv_asum = sval;
    __syncthreads();

    int w = t >> 6, f = t & 63;
    float racc = 0.f;
    for (int n = s+w; n < en; n += 16) racc += e[n]*h[(size_t)n*64 + f];
    red[t] = racc; __syncthreads();
    if (w == 0) {
        float a = 0.f;
        #pragma unroll
        for (int i = 0; i < 16; ++i) a += red[i*64 + f];
        rp[f] = a*inv_asum;
    }
    __syncthreads();

    if (t < 64) {
        float qv = q_val(lbih, lbhh, t);
        float p0 = qv*Wout[t*2]   + rp[t]*Wout[(64+t)*2];
        float p1 = qv*Wout[t*2+1] + rp[t]*Wout[(64+t)*2+1];
        #pragma unroll
        for (int off = 32; off; off >>= 1) { p0 += __shfl_xor(p0, off); p1 += __shfl_xor(p1, off); }
        if (t == 0) { out[g*2] = p0 + bout[0]; out[g*2+1] = p1 + bout[1]; }
    }
}

extern "C" void kernel_launch(void* const* d_in, const int* in_sizes, int n_in,
                              void* d_out, int out_size, void* d_ws, size_t ws_size,
                              hipStream_t stream)
{
    const float* x      = (const float*)d_in[0];
    const float* ea     = (const float*)d_in[1];
    const int*   ei     = (const int*)  d_in[2];
    const int*   batch  = (const int*)  d_in[3];
    const float* W0     = (const float*)d_in[4];
    const float* b0     = (const float*)d_in[5];
    const float* We1    = (const float*)d_in[6];
    const float* be1    = (const float*)d_in[7];
    const float* We2    = (const float*)d_in[8];
    const float* be2    = (const float*)d_in[9];
    const float* root   = (const float*)d_in[10];
    const float* conv_b = (const float*)d_in[11];
    const float* Wih    = (const float*)d_in[12];
    const float* Whh    = (const float*)d_in[13];
    const float* bih    = (const float*)d_in[14];
    const float* bhh    = (const float*)d_in[15];
    const float* lbih   = (const float*)d_in[18];
    const float* lbhh   = (const float*)d_in[19];
    const float* Wout   = (const float*)d_in[20];
    const float* bout   = (const float*)d_in[21];
    float* out = (float*)d_out;

    float* W = (float*)d_ws;
    size_t off = 0;
    float* h       = W + off; off += (size_t)NN*64;
    float* he      = W + off; off += (size_t)NE*64;
    float* he_srt  = W + off; off += (size_t)NE*64;
    float* agg     = W + off; off += (size_t)NN*64;
    float* W8T     = W + off; off += 32768;
    float* inv_deg = W + off; off += NN;
    float* e       = W + off; off += NN;
    int*   deg     = (int*)(W + off); off += NN;   // deg+cnt contiguous: one memset
    int*   cnt     = (int*)(W + off); off += NN;
    int*   offs    = (int*)(W + off); off += NN+1;
    int*   srcs    = (int*)(W + off); off += NE;
    int*   dsts    = (int*)(W + off); off += NE;
    int*   perm    = (int*)(W + off); off += NE;
    int*   gstart  = (int*)(W + off); off += BG;
    int*   gend    = (int*)(W + off); off += BG;

    hipMemsetAsync(deg, 0, 2*NN*sizeof(int), stream);
    hipMemsetAsync(agg, 0, (size_t)NN*64*sizeof(float), stream);
    setup_kernel<<<4096, 256, 0, stream>>>(x, ea, ei, W0, b0, We1, be1, Wih, Whh,
                                           W8T, h, he, deg, cnt);
    scan_kernel<<<1, 256, 0, stream>>>(cnt, offs);
    scatter_kernel<<<64, 256, 0, stream>>>(ei, offs, cnt, srcs, dsts, perm);
    reorder_kernel<<<4096, 256, 0, stream>>>(he, perm, he_srt);
    inv_range_kernel<<<16, 256, 0, stream>>>(deg, batch, inv_deg, gstart, gend);

    for (int it = 0; it < 6; ++it) {
        conv_kernel<<<NN/NT, 1024, 0, stream>>>(h, We2, be2, he_srt,
                                                offs, srcs, dsts, agg);
        node_kernel<<<NN/8, 512, 0, stream>>>(W8T, root, conv_b,
                                              inv_deg, bih, bhh, h, agg);
    }

    e_kernel<<<NN/4, 256, 0, stream>>>(h, lbih, lbhh, e);
    pool_kernel<<<BG, 1024, 0, stream>>>(h, e, gstart, gend, lbih, lbhh, Wout, bout, out);
}

// Round 10
// 1393.640 us; speedup vs baseline: 1.3167x; 1.3167x over previous
//
#include <hip/hip_runtime.h>
#include <hip/hip_cooperative_groups.h>
#include <cstddef>

namespace cg = cooperative_groups;

#define NE 16384
#define NN 4096
#define BG 16
#define NT 16      // nodes per conv tile
#define ACH 8      // a-chunk size (8 chunks of 8 = 64), double-buffered

__device__ __forceinline__ float lrelu(float v){ return v >= 0.f ? v : 0.01f*v; }
__device__ __forceinline__ float sigm(float v){ return 1.f/(1.f + expf(-v)); }
__device__ __forceinline__ void fma4(float4& a, float s, const float4& w){
    a.x += s*w.x; a.y += s*w.y; a.z += s*w.z; a.w += s*w.w;
}

// ---------------- setup: W8T, h0, he, deg(dst), cnt(src) ----------------
__global__ __launch_bounds__(256) void setup_kernel(
    const float* __restrict__ x, const float* __restrict__ ea,
    const int* __restrict__ ei,
    const float* __restrict__ W0, const float* __restrict__ b0,
    const float* __restrict__ We1, const float* __restrict__ be1,
    const float* __restrict__ Wih, const float* __restrict__ Whh,
    float* __restrict__ W8T,
    float* __restrict__ h, float* __restrict__ he,
    int* __restrict__ deg, int* __restrict__ cnt)
{
    int t = blockIdx.x*256 + threadIdx.x;   // grid: 4096x256 = 1048576
    {   // he: [E,64]  lrelu(edge_attr @ We1 + be1)
        int e = t >> 6, f = t & 63;
        float v = be1[f];
        #pragma unroll
        for (int d = 0; d < 4; ++d) v += ea[e*4+d]*We1[d*64+f];
        he[t] = lrelu(v);
    }
    if (t < NN*64) {    // h0 = lrelu(x @ W0 + b0)
        int n = t >> 6, f = t & 63;
        float v = b0[f];
        #pragma unroll
        for (int d = 0; d < 3; ++d) v += x[n*3+d]*W0[d*64+f];
        h[t] = lrelu(v);
    }
    if (t < 32768) {    // W8T[k][g][8] = {Wih_r,Wih_z,Wih_n,Whh_r,Whh_z,Whh_n,0,0}
        int k = t >> 9, g = (t >> 3) & 63, j = t & 7;
        float v = 0.f;
        if (j < 3)      v = Wih[(j*64+g)*64 + k];
        else if (j < 6) v = Whh[((j-3)*64+g)*64 + k];
        W8T[t] = v;
    }
    if (t < NE) {
        atomicAdd(&deg[ei[NE + t]], 1);   // in-degree (dst) for mean aggr
        atomicAdd(&cnt[ei[t]], 1);        // out-degree (src) for edge sort
    }
}

// ---------- scan of cnt -> offs  +  inv_deg / per-graph ranges (1 block) ----------
__global__ __launch_bounds__(256) void scan_inv_kernel(
    const int* __restrict__ cnt, int* __restrict__ offs,
    const int* __restrict__ deg, const int* __restrict__ batch,
    float* __restrict__ inv_deg, int* __restrict__ gstart, int* __restrict__ gend)
{
    __shared__ int ps[256];
    int t = threadIdx.x;
    int base = t*16;
    int loc[16];
    int s = 0;
    #pragma unroll
    for (int i = 0; i < 16; ++i) { loc[i] = s; s += cnt[base+i]; }
    ps[t] = s; __syncthreads();
    for (int off = 1; off < 256; off <<= 1) {
        int v = 0;
        if (t >= off) v = ps[t-off];
        __syncthreads();
        if (t >= off) ps[t] += v;
        __syncthreads();
    }
    int pre = (t == 0) ? 0 : ps[t-1];
    #pragma unroll
    for (int i = 0; i < 16; ++i) offs[base+i] = pre + loc[i];
    if (t == 255) offs[NN] = pre + s;

    // fused inv_range (per-node, same logic as the old kernel)
    for (int i = 0; i < 16; ++i) {
        int n = base + i;
        inv_deg[n] = 1.f / fmaxf((float)deg[n], 1.f);
        int b  = batch[n];
        int bp = (n == 0)    ? -1 : batch[n-1];
        int bn = (n == NN-1) ? BG : batch[n+1];
        for (int g = bp+1; g <= b; ++g) gstart[g] = n;
        for (int g = b;   g <  bn; ++g) gend[g]   = n+1;
        if (n == 0)    for (int g = 0;   g < b;  ++g) gend[g]   = 0;
        if (n == NN-1) for (int g = b+1; g < BG; ++g) gstart[g] = NN;
    }
}

// ---------------- scatter: build src-sorted edge arrays ----------------
__global__ __launch_bounds__(256) void scatter_kernel(
    const int* __restrict__ ei, const int* __restrict__ offs,
    int* __restrict__ cnt,  // consumed as cursor via atomicSub
    int* __restrict__ srcs, int* __restrict__ dsts, int* __restrict__ perm)
{
    int e = blockIdx.x*256 + threadIdx.x;
    if (e >= NE) return;
    int s = ei[e], d = ei[NE + e];
    int old = atomicSub(&cnt[s], 1);
    int pos = offs[s] + old - 1;
    srcs[pos] = s; dsts[pos] = d; perm[pos] = e;
}

// ---------------- gather he rows into src-sorted order ----------------
__global__ __launch_bounds__(256) void reorder_kernel(
    const float* __restrict__ he, const int* __restrict__ perm,
    float* __restrict__ he_srt)
{
    int t = blockIdx.x*256 + threadIdx.x;   // 4096 x 256 = NE*64
    he_srt[t] = he[(size_t)perm[t>>6]*64 + (t & 63)];
}

__device__ __forceinline__ float q_val(const float* lbih, const float* lbhh, int g)
{
    float gi = lbih[g]     + lbhh[g];
    float gg = lbih[128+g] + lbhh[128+g];
    float go = lbih[192+g] + lbhh[192+g];
    return sigm(go)*tanhf(sigm(gi)*tanhf(gg));   // hl0=cl0=q_star0=0
}

// ================= mega kernel: 6 x (conv + node) + finale ==================
// Cooperative, grid 256 x 1024 (1 block/CU). Conv phase = R5's proven
// producer/consumer code (64 VGPR, no spill). One grid.sync per iteration
// (conv->node); agg double-buffered by it&1 so node(k)'s zeroing never races
// next iteration's atomics. h tile lives in LDS (hsT) across iterations; node
// phase updates it in place. he_all staged ONCE (edge data is iter-invariant).
// Blocks 0..15 run the pooled finale after a final grid.sync.
__global__ __launch_bounds__(1024) void mega_kernel(
    float* __restrict__ h, const float* __restrict__ We2,
    const float* __restrict__ be2, const float* __restrict__ he_srt,
    const int* __restrict__ offs, const int* __restrict__ srcs,
    const int* __restrict__ dsts, float* __restrict__ agg,
    const float* __restrict__ W8T, const float* __restrict__ root,
    const float* __restrict__ conv_b, const float* __restrict__ inv_deg,
    const float* __restrict__ bih, const float* __restrict__ bhh,
    const int* __restrict__ gstart, const int* __restrict__ gend,
    const float* __restrict__ lbih, const float* __restrict__ lbhh,
    const float* __restrict__ Wout, const float* __restrict__ bout,
    float* __restrict__ ebuf, float* __restrict__ out)
{
    __shared__ float hsT[64][NT];          // h tile [i][n], persistent   4 KB
    __shared__ float Tb [NT][64];          // msg bias                    4 KB
    __shared__ float Tc [2][ACH][NT][64];  // T chunk dbuf               64 KB
    __shared__ float he_all[128][72];      // all chunks, slots<128      36 KB
    __shared__ float ms [NT][64];          // node phase                  4 KB
    __shared__ float red[1024];            // pool                        4 KB
    __shared__ float qs[64];
    __shared__ float rp[64];
    __shared__ float sval;

    cg::grid_group grid = cg::this_grid();
    int t  = threadIdx.x;
    int n0 = blockIdx.x * NT;
    int ebase = offs[n0];
    int ecnt  = offs[n0+NT] - ebase;
    int eend  = ebase + ecnt;

    {   // stage h tile [i][n] (1024 elems, once; node phase maintains it)
        int n = t >> 6, i = t & 63;
        hsT[i][n] = h[(size_t)(n0+n)*64 + i];
    }
    #pragma unroll
    for (int r = 0; r < 2; ++r) {   // stage he_all once (slots 0..127, 64 a)
        int idx = t + r*1024;
        int sl = idx >> 4, a4 = (idx & 15) * 4;
        if (ebase + sl < NE)
            *(float4*)&he_all[sl][a4] =
                *(const float4*)&he_srt[(size_t)(ebase+sl)*64 + a4];
    }

    // producer mapping (t < 512)  [R5 proven]
    int aT = t >> 6;               // 0..7  a' within chunk
    int nT = ((t >> 4) & 3) * 4;   // 4 nodes per thread
    int fT = (t & 15) * 4;         // 4 f per thread
    // consumer mapping + persistent edge state (t >= 512), graph-static
    int ct   = t - 512;
    int slot = ct >> 4;            // 0..31 edge slots
    int f4   = (ct & 15) * 4;      // 4 output features per thread
    int nl0=-1,dt0=0,nl1=-1,dt1=0,nl2=-1,dt2=0,nl3=-1,dt3=0;
    if (t >= 512) {
        if (slot      < ecnt) { nl0 = srcs[ebase+slot]    - n0; dt0 = dsts[ebase+slot];    }
        if (slot + 32 < ecnt) { nl1 = srcs[ebase+slot+32] - n0; dt1 = dsts[ebase+slot+32]; }
        if (slot + 64 < ecnt) { nl2 = srcs[ebase+slot+64] - n0; dt2 = dsts[ebase+slot+64]; }
        if (slot + 96 < ecnt) { nl3 = srcs[ebase+slot+96] - n0; dt3 = dsts[ebase+slot+96]; }
    }
    __syncthreads();

#define EDGE_ACC(mj, nlj, row, cm, buf_) \
    if (nlj >= 0) { \
        float4 hA = *(const float4*)&he_all[row][(cm)*8]; \
        float4 hB = *(const float4*)&he_all[row][(cm)*8 + 4]; \
        float he8[8] = {hA.x,hA.y,hA.z,hA.w,hB.x,hB.y,hB.z,hB.w}; \
        _Pragma("unroll") \
        for (int a_ = 0; a_ < 8; ++a_) { \
            float4 tv = *(const float4*)&Tc[buf_][a_][nlj][f4]; \
            fma4(mj, he8[a_], tv); \
        } \
    }

#define CONSUME(cm) { \
    int buf_ = (cm) & 1; \
    EDGE_ACC(m0, nl0, (slot),      cm, buf_) \
    EDGE_ACC(m1, nl1, (slot+32),   cm, buf_) \
    EDGE_ACC(m2, nl2, (slot+64),   cm, buf_) \
    EDGE_ACC(m3, nl3, (slot+96),   cm, buf_) \
    for (int e = ebase + 128 + slot; e < eend; e += 32) { \
        int nl = srcs[e] - n0, dtv = dsts[e]; \
        const float* hep = he_srt + (size_t)e*64 + (cm)*ACH; \
        float4 pm = {0,0,0,0}; \
        _Pragma("unroll") \
        for (int a_ = 0; a_ < 8; ++a_) { \
            float hv = hep[a_]; \
            float4 tv = *(const float4*)&Tc[buf_][a_][nl][f4]; \
            fma4(pm, hv, tv); \
        } \
        if ((cm) == 0) { \
            float4 b = *(const float4*)&Tb[nl][f4]; \
            pm.x += b.x; pm.y += b.y; pm.z += b.z; pm.w += b.w; \
        } \
        float* ap = aggp + (size_t)dtv*64 + f4; \
        atomicAdd(ap+0, pm.x); atomicAdd(ap+1, pm.y); \
        atomicAdd(ap+2, pm.z); atomicAdd(ap+3, pm.w); \
    } \
}

    for (int it = 0; it < 6; ++it) {
        float* aggp = agg + (size_t)(it & 1) * NN * 64;
        float4 m0={0,0,0,0},m1={0,0,0,0},m2={0,0,0,0},m3={0,0,0,0};

        // ---------------- conv phase (R5 structure) ----------------
        for (int c = 0; c < 8; ++c) {
            if (t < 512) {
                // producer: T chunk c -> Tc[c&1]
                const float* Wp = We2 + (size_t)(c*ACH + aT)*4096 + fT;
                float4 A0={0,0,0,0},A1={0,0,0,0},A2={0,0,0,0},A3={0,0,0,0};
                #pragma unroll 8
                for (int i = 0; i < 64; ++i) {
                    float4 w  = *(const float4*)(Wp + (size_t)i*64);
                    float4 hv = *(const float4*)&hsT[i][nT];
                    A0.x += hv.x*w.x; A0.y += hv.x*w.y; A0.z += hv.x*w.z; A0.w += hv.x*w.w;
                    A1.x += hv.y*w.x; A1.y += hv.y*w.y; A1.z += hv.y*w.z; A1.w += hv.y*w.w;
                    A2.x += hv.z*w.x; A2.y += hv.z*w.y; A2.z += hv.z*w.z; A2.w += hv.z*w.w;
                    A3.x += hv.w*w.x; A3.y += hv.w*w.y; A3.z += hv.w*w.z; A3.w += hv.w*w.w;
                }
                int buf = c & 1;
                *(float4*)&Tc[buf][aT][nT+0][fT] = A0;
                *(float4*)&Tc[buf][aT][nT+1][fT] = A1;
                *(float4*)&Tc[buf][aT][nT+2][fT] = A2;
                *(float4*)&Tc[buf][aT][nT+3][fT] = A3;
            } else {
                if (c == 0) {
                    // Tb[n][f] = sum_i h[n,i]*be2[i*64+f]  (per iter, h changed)
                    int n = ct >> 5, fp = (ct & 31) * 2;
                    float t0 = 0.f, t1 = 0.f;
                    #pragma unroll 8
                    for (int i = 0; i < 64; ++i) {
                        float hv = hsT[i][n];
                        float2 b = *(const float2*)&be2[(size_t)i*64 + fp];
                        t0 += hv*b.x; t1 += hv*b.y;
                    }
                    Tb[n][fp]   = t0;
                    Tb[n][fp+1] = t1;
                } else {
                    CONSUME(c-1);
                }
            }
            __syncthreads();
        }
        if (t >= 512) {
            CONSUME(7);
            // scatter: one atomic add per edge (msg + bias)
            if (nl0 >= 0) {
                float4 b = *(const float4*)&Tb[nl0][f4];
                float* ap = aggp + (size_t)dt0*64 + f4;
                atomicAdd(ap+0, m0.x+b.x); atomicAdd(ap+1, m0.y+b.y);
                atomicAdd(ap+2, m0.z+b.z); atomicAdd(ap+3, m0.w+b.w);
            }
            if (nl1 >= 0) {
                float4 b = *(const float4*)&Tb[nl1][f4];
                float* ap = aggp + (size_t)dt1*64 + f4;
                atomicAdd(ap+0, m1.x+b.x); atomicAdd(ap+1, m1.y+b.y);
                atomicAdd(ap+2, m1.z+b.z); atomicAdd(ap+3, m1.w+b.w);
            }
            if (nl2 >= 0) {
                float4 b = *(const float4*)&Tb[nl2][f4];
                float* ap = aggp + (size_t)dt2*64 + f4;
                atomicAdd(ap+0, m2.x+b.x); atomicAdd(ap+1, m2.y+b.y);
                atomicAdd(ap+2, m2.z+b.z); atomicAdd(ap+3, m2.w+b.w);
            }
            if (nl3 >= 0) {
                float4 b = *(const float4*)&Tb[nl3][f4];
                float* ap = aggp + (size_t)dt3*64 + f4;
                atomicAdd(ap+0, m3.x+b.x); atomicAdd(ap+1, m3.y+b.y);
                atomicAdd(ap+2, m3.z+b.z); atomicAdd(ap+3, m3.w+b.w);
            }
        }
        __threadfence();
        grid.sync();   // all agg atomics visible -> node phase

        // ---------------- node phase: m, gi, gh + GRU (own 16 nodes) --------
        {
            int n = t >> 6, g = t & 63;   // wave-uniform n
            int gn = n0 + n;
            size_t ix = (size_t)gn*64 + g;
            float v = aggp[ix]*inv_deg[gn] + conv_b[g];
            aggp[ix] = 0.f;               // ready for iteration it+2
            #pragma unroll 8
            for (int k = 0; k < 64; ++k) v += hsT[k][n]*root[k*64 + g];
            ms[n][g] = lrelu(v);
            __syncthreads();

            float ir=0.f, iz=0.f, in_=0.f, hr=0.f, hz=0.f, hn=0.f;
            const float* Wp = W8T + (size_t)g*8;
            #pragma unroll 8
            for (int k = 0; k < 64; ++k) {
                float am = ms[n][k], ah = hsT[k][n];
                float4 w0 = *(const float4*)(Wp + (size_t)k*512);
                float4 w1 = *(const float4*)(Wp + (size_t)k*512 + 4);
                ir  += am*w0.x; iz += am*w0.y; in_ += am*w0.z;
                hr  += ah*w0.w; hz += ah*w1.x; hn  += ah*w1.y;
            }
            float r  = sigm(ir + bih[g]      + hr + bhh[g]);
            float z  = sigm(iz + bih[64+g]   + hz + bhh[64+g]);
            float nn = tanhf(in_ + bih[128+g] + r*(hn + bhh[128+g]));
            float ho = hsT[g][n];
            float hnew = (1.f - z)*nn + z*ho;
            __syncthreads();              // all old-h reads done
            hsT[g][n] = hnew;             // LDS h for next conv iter
            h[ix] = hnew;                 // global h for the finale
            __syncthreads();
        }
    }

    __threadfence();
    grid.sync();   // all blocks' final h visible

    // ---------------- finale: blocks 0..15 = one graph each ----------------
    if (blockIdx.x >= BG) return;
    {
        int g = blockIdx.x;
        int s = gstart[g], en = gend[g];
        if (t < 64) qs[t] = q_val(lbih, lbhh, t);
        __syncthreads();
        int w = t >> 6, f = t & 63;
        for (int n = s + w; n < en; n += 16) {   // e[n] = h[n] . q
            float p = h[(size_t)n*64 + f]*qs[f];
            #pragma unroll
            for (int off = 32; off; off >>= 1) p += __shfl_xor(p, off);
            if (f == 0) ebuf[n] = p;
        }
        __syncthreads();

        float mx = -1e30f;
        for (int n = s+t; n < en; n += 1024) mx = fmaxf(mx, ebuf[n]);
        red[t] = mx; __syncthreads();
        for (int st = 512; st; st >>= 1) { if (t < st) red[t] = fmaxf(red[t], red[t+st]); __syncthreads(); }
        if (t == 0) sval = red[0];
        __syncthreads();
        float lmx = sval;
        __syncthreads();

        float sm = 0.f;
        for (int n = s+t; n < en; n += 1024) { float a = expf(ebuf[n]-lmx); ebuf[n] = a; sm += a; }
        red[t] = sm; __syncthreads();
        for (int st = 512; st; st >>= 1) { if (t < st) red[t] += red[t+st]; __syncthreads(); }
        if (t == 0) sval = (red[0] > 0.f) ? 1.f/red[0] : 0.f;
        __syncthreads();
        float inv_asum = sval;
        __syncthreads();

        float racc = 0.f;
        for (int n = s+w; n < en; n += 16) racc += ebuf[n]*h[(size_t)n*64 + f];
        red[t] = racc; __syncthreads();
        if (w == 0) {
            float a = 0.f;
            #pragma unroll
            for (int i = 0; i < 16; ++i) a += red[i*64 + f];
            rp[f] = a*inv_asum;
        }
        __syncthreads();

        if (t < 64) {
            float qv = qs[t];
            float p0 = qv*Wout[t*2]   + rp[t]*Wout[(64+t)*2];
            float p1 = qv*Wout[t*2+1] + rp[t]*Wout[(64+t)*2+1];
            #pragma unroll
            for (int off = 32; off; off >>= 1) { p0 += __shfl_xor(p0, off); p1 += __shfl_xor(p1, off); }
            if (t == 0) { out[g*2] = p0 + bout[0]; out[g*2+1] = p1 + bout[1]; }
        }
    }
#undef CONSUME
#undef EDGE_ACC
}

extern "C" void kernel_launch(void* const* d_in, const int* in_sizes, int n_in,
                              void* d_out, int out_size, void* d_ws, size_t ws_size,
                              hipStream_t stream)
{
    const float* x      = (const float*)d_in[0];
    const float* ea     = (const float*)d_in[1];
    const int*   ei     = (const int*)  d_in[2];
    const int*   batch  = (const int*)  d_in[3];
    const float* W0     = (const float*)d_in[4];
    const float* b0     = (const float*)d_in[5];
    const float* We1    = (const float*)d_in[6];
    const float* be1    = (const float*)d_in[7];
    const float* We2    = (const float*)d_in[8];
    const float* be2    = (const float*)d_in[9];
    const float* root   = (const float*)d_in[10];
    const float* conv_b = (const float*)d_in[11];
    const float* Wih    = (const float*)d_in[12];
    const float* Whh    = (const float*)d_in[13];
    const float* bih    = (const float*)d_in[14];
    const float* bhh    = (const float*)d_in[15];
    const float* lbih   = (const float*)d_in[18];
    const float* lbhh   = (const float*)d_in[19];
    const float* Wout   = (const float*)d_in[20];
    const float* bout   = (const float*)d_in[21];
    float* out = (float*)d_out;

    float* W = (float*)d_ws;
    size_t off = 0;
    float* h       = W + off; off += (size_t)NN*64;
    float* he      = W + off; off += (size_t)NE*64;
    float* he_srt  = W + off; off += (size_t)NE*64;
    float* agg     = W + off; off += (size_t)2*NN*64;   // dbuf by it&1
    float* W8T     = W + off; off += 32768;
    float* inv_deg = W + off; off += NN;
    float* e       = W + off; off += NN;
    int*   deg     = (int*)(W + off); off += NN;   // deg+cnt contiguous: one memset
    int*   cnt     = (int*)(W + off); off += NN;
    int*   offs    = (int*)(W + off); off += NN+1;
    int*   srcs    = (int*)(W + off); off += NE;
    int*   dsts    = (int*)(W + off); off += NE;
    int*   perm    = (int*)(W + off); off += NE;
    int*   gstart  = (int*)(W + off); off += BG;
    int*   gend    = (int*)(W + off); off += BG;

    hipMemsetAsync(deg, 0, 2*NN*sizeof(int), stream);
    hipMemsetAsync(agg, 0, (size_t)2*NN*64*sizeof(float), stream);
    setup_kernel<<<4096, 256, 0, stream>>>(x, ea, ei, W0, b0, We1, be1, Wih, Whh,
                                           W8T, h, he, deg, cnt);
    scan_inv_kernel<<<1, 256, 0, stream>>>(cnt, offs, deg, batch,
                                           inv_deg, gstart, gend);
    scatter_kernel<<<64, 256, 0, stream>>>(ei, offs, cnt, srcs, dsts, perm);
    reorder_kernel<<<4096, 256, 0, stream>>>(he, perm, he_srt);

    void* params[] = {
        (void*)&h, (void*)&We2, (void*)&be2, (void*)&he_srt,
        (void*)&offs, (void*)&srcs, (void*)&dsts, (void*)&agg,
        (void*)&W8T, (void*)&root, (void*)&conv_b, (void*)&inv_deg,
        (void*)&bih, (void*)&bhh, (void*)&gstart, (void*)&gend,
        (void*)&lbih, (void*)&lbhh, (void*)&Wout, (void*)&bout,
        (void*)&e, (void*)&out
    };
    hipLaunchCooperativeKernel((void*)mega_kernel, dim3(256), dim3(1024),
                               params, 0, stream);
}

// Round 11
// 588.097 us; speedup vs baseline: 3.1203x; 2.3697x over previous
//
#include <hip/hip_runtime.h>
#include <cstddef>

#define NE 16384
#define NN 4096
#define BG 16
#define NT 16      // nodes per conv tile
#define ACH 8      // a-chunk size (8 chunks of 8 = 64), double-buffered

__device__ __forceinline__ float lrelu(float v){ return v >= 0.f ? v : 0.01f*v; }
__device__ __forceinline__ float sigm(float v){ return 1.f/(1.f + expf(-v)); }

// ---------------- setup: W8T, h0, he, deg(dst), cnt(src) ----------------
__global__ __launch_bounds__(256) void setup_kernel(
    const float* __restrict__ x, const float* __restrict__ ea,
    const int* __restrict__ ei,
    const float* __restrict__ W0, const float* __restrict__ b0,
    const float* __restrict__ We1, const float* __restrict__ be1,
    const float* __restrict__ Wih, const float* __restrict__ Whh,
    float* __restrict__ W8T,
    float* __restrict__ h, float* __restrict__ he,
    int* __restrict__ deg, int* __restrict__ cnt)
{
    int t = blockIdx.x*256 + threadIdx.x;   // grid: 4096x256 = 1048576
    {   // he: [E,64]  lrelu(edge_attr @ We1 + be1)
        int e = t >> 6, f = t & 63;
        float v = be1[f];
        #pragma unroll
        for (int d = 0; d < 4; ++d) v += ea[e*4+d]*We1[d*64+f];
        he[t] = lrelu(v);
    }
    if (t < NN*64) {    // h0 = lrelu(x @ W0 + b0)
        int n = t >> 6, f = t & 63;
        float v = b0[f];
        #pragma unroll
        for (int d = 0; d < 3; ++d) v += x[n*3+d]*W0[d*64+f];
        h[t] = lrelu(v);
    }
    if (t < 32768) {    // W8T[k][g][8] = {Wih_r,Wih_z,Wih_n,Whh_r,Whh_z,Whh_n,0,0}
        int k = t >> 9, g = (t >> 3) & 63, j = t & 7;
        float v = 0.f;
        if (j < 3)      v = Wih[(j*64+g)*64 + k];
        else if (j < 6) v = Whh[((j-3)*64+g)*64 + k];
        W8T[t] = v;
    }
    if (t < NE) {
        atomicAdd(&deg[ei[NE + t]], 1);   // in-degree (dst) for mean aggr
        atomicAdd(&cnt[ei[t]], 1);        // out-degree (src) for edge sort
    }
}

// ---------- scan of cnt -> offs  +  inv_deg / per-graph ranges (1 block) ----------
__global__ __launch_bounds__(256) void scan_inv_kernel(
    const int* __restrict__ cnt, int* __restrict__ offs,
    const int* __restrict__ deg, const int* __restrict__ batch,
    float* __restrict__ inv_deg, int* __restrict__ gstart, int* __restrict__ gend)
{
    __shared__ int ps[256];
    int t = threadIdx.x;
    int base = t*16;
    int loc[16];
    int s = 0;
    #pragma unroll
    for (int i = 0; i < 16; ++i) { loc[i] = s; s += cnt[base+i]; }
    ps[t] = s; __syncthreads();
    for (int off = 1; off < 256; off <<= 1) {
        int v = 0;
        if (t >= off) v = ps[t-off];
        __syncthreads();
        if (t >= off) ps[t] += v;
        __syncthreads();
    }
    int pre = (t == 0) ? 0 : ps[t-1];
    #pragma unroll
    for (int i = 0; i < 16; ++i) offs[base+i] = pre + loc[i];
    if (t == 255) offs[NN] = pre + s;

    // fused inv_range (per-node, same logic as the old standalone kernel)
    for (int i = 0; i < 16; ++i) {
        int n = base + i;
        inv_deg[n] = 1.f / fmaxf((float)deg[n], 1.f);
        int b  = batch[n];
        int bp = (n == 0)    ? -1 : batch[n-1];
        int bn = (n == NN-1) ? BG : batch[n+1];
        for (int g = bp+1; g <= b; ++g) gstart[g] = n;
        for (int g = b;   g <  bn; ++g) gend[g]   = n+1;
        if (n == 0)    for (int g = 0;   g < b;  ++g) gend[g]   = 0;
        if (n == NN-1) for (int g = b+1; g < BG; ++g) gstart[g] = NN;
    }
}

// ---------------- scatter: build src-sorted edge arrays ----------------
__global__ __launch_bounds__(256) void scatter_kernel(
    const int* __restrict__ ei, const int* __restrict__ offs,
    int* __restrict__ cnt,  // consumed as cursor via atomicSub
    int* __restrict__ srcs, int* __restrict__ dsts, int* __restrict__ perm)
{
    int e = blockIdx.x*256 + threadIdx.x;
    if (e >= NE) return;
    int s = ei[e], d = ei[NE + e];
    int old = atomicSub(&cnt[s], 1);
    int pos = offs[s] + old - 1;
    srcs[pos] = s; dsts[pos] = d; perm[pos] = e;
}

// ---------------- gather he rows into src-sorted order ----------------
__global__ __launch_bounds__(256) void reorder_kernel(
    const float* __restrict__ he, const int* __restrict__ perm,
    float* __restrict__ he_srt)
{
    int t = blockIdx.x*256 + threadIdx.x;   // 4096 x 256 = NE*64
    he_srt[t] = he[(size_t)perm[t>>6]*64 + (t & 63)];
}

// ---------------- fused conv: producer/consumer wave role-split (R5) ----------------
// R5's proven structure (557.95 us total; 64 VGPR, no spill). One delta,
// individually validated in R7-R9: Tb is computed by CONSUMER waves during
// chunk 0 (overlapped with producer chunk-0 GEMM) instead of serially by
// producers after it. R6-R10 lesson: every larger restructure of this kernel
// spills at the immovable 64-VGPR cap and loses 2-4x; do not add live state.
__global__ __launch_bounds__(1024) void conv_kernel(
    const float* __restrict__ h, const float* __restrict__ We2,
    const float* __restrict__ be2, const float* __restrict__ he_srt,
    const int* __restrict__ offs, const int* __restrict__ srcs,
    const int* __restrict__ dsts, float* __restrict__ agg)
{
    __shared__ float hsT[64][NT];          // 4 KB
    __shared__ float Tb [NT][64];          // 4 KB
    __shared__ float Tc [2][ACH][NT][64];  // 64 KB (double-buffered)
    __shared__ float he_s[2][128][ACH];    // 8 KB  (double-buffered) -> 80 KB
    int t  = threadIdx.x;
    int n0 = blockIdx.x * NT;

    { int n = t >> 6, i = t & 63; hsT[i][n] = h[(size_t)(n0+n)*64 + i]; }
    int ebase = offs[n0];
    int ecnt  = offs[n0+NT] - ebase;
    int eend  = ebase + ecnt;
    __syncthreads();

    // producer mapping (t < 512)
    int aT = t >> 6;               // 0..7  a' within chunk
    int nT = ((t >> 4) & 3) * 4;   // 4 nodes per thread
    int fT = (t & 15) * 4;         // 4 f per thread
    // consumer mapping + persistent state (t >= 512)
    int ct   = t - 512;
    int slot = ct >> 4;            // 0..31 edge slots
    int f4   = (ct & 15) * 4;      // 4 output features per thread
    int nl0=-1,dt0=0,nl1=-1,dt1=0,nl2=-1,dt2=0,nl3=-1,dt3=0;
    float4 m0={0,0,0,0},m1={0,0,0,0},m2={0,0,0,0},m3={0,0,0,0};
    if (t >= 512) {
        if (slot      < ecnt) { nl0 = srcs[ebase+slot]    - n0; dt0 = dsts[ebase+slot];    }
        if (slot + 32 < ecnt) { nl1 = srcs[ebase+slot+32] - n0; dt1 = dsts[ebase+slot+32]; }
        if (slot + 64 < ecnt) { nl2 = srcs[ebase+slot+64] - n0; dt2 = dsts[ebase+slot+64]; }
        if (slot + 96 < ecnt) { nl3 = srcs[ebase+slot+96] - n0; dt3 = dsts[ebase+slot+96]; }
    }

#define EDGE_ACC(mj, nlj, row, buf_) \
    if (nlj >= 0) { \
        float4 hA = *(const float4*)&he_s[buf_][row][0]; \
        float4 hB = *(const float4*)&he_s[buf_][row][4]; \
        float4 t0 = *(const float4*)&Tc[buf_][0][nlj][f4]; \
        float4 t1 = *(const float4*)&Tc[buf_][1][nlj][f4]; \
        float4 t2 = *(const float4*)&Tc[buf_][2][nlj][f4]; \
        float4 t3 = *(const float4*)&Tc[buf_][3][nlj][f4]; \
        float4 t4 = *(const float4*)&Tc[buf_][4][nlj][f4]; \
        float4 t5 = *(const float4*)&Tc[buf_][5][nlj][f4]; \
        float4 t6 = *(const float4*)&Tc[buf_][6][nlj][f4]; \
        float4 t7 = *(const float4*)&Tc[buf_][7][nlj][f4]; \
        mj.x += hA.x*t0.x+hA.y*t1.x+hA.z*t2.x+hA.w*t3.x+hB.x*t4.x+hB.y*t5.x+hB.z*t6.x+hB.w*t7.x; \
        mj.y += hA.x*t0.y+hA.y*t1.y+hA.z*t2.y+hA.w*t3.y+hB.x*t4.y+hB.y*t5.y+hB.z*t6.y+hB.w*t7.y; \
        mj.z += hA.x*t0.z+hA.y*t1.z+hA.z*t2.z+hA.w*t3.z+hB.x*t4.z+hB.y*t5.z+hB.z*t6.z+hB.w*t7.z; \
        mj.w += hA.x*t0.w+hA.y*t1.w+hA.z*t2.w+hA.w*t3.w+hB.x*t4.w+hB.y*t5.w+hB.z*t6.w+hB.w*t7.w; \
    }

#define CONSUME(cm) { \
    int buf_ = (cm) & 1; \
    EDGE_ACC(m0, nl0, (slot),      buf_) \
    EDGE_ACC(m1, nl1, (slot+32),   buf_) \
    EDGE_ACC(m2, nl2, (slot+64),   buf_) \
    EDGE_ACC(m3, nl3, (slot+96),   buf_) \
    for (int e = ebase + 128 + slot; e < eend; e += 32) { \
        int nl = srcs[e] - n0, dtv = dsts[e]; \
        const float* hep = he_srt + (size_t)e*64 + (cm)*ACH; \
        float4 pm = {0,0,0,0}; \
        _Pragma("unroll") \
        for (int a = 0; a < ACH; ++a) { \
            float hv = hep[a]; \
            float4 tv = *(const float4*)&Tc[buf_][a][nl][f4]; \
            pm.x += hv*tv.x; pm.y += hv*tv.y; pm.z += hv*tv.z; pm.w += hv*tv.w; \
        } \
        if ((cm) == 0) { \
            float4 b = *(const float4*)&Tb[nl][f4]; \
            pm.x += b.x; pm.y += b.y; pm.z += b.z; pm.w += b.w; \
        } \
        float* ap = agg + (size_t)dtv*64 + f4; \
        atomicAdd(ap+0, pm.x); atomicAdd(ap+1, pm.y); \
        atomicAdd(ap+2, pm.z); atomicAdd(ap+3, pm.w); \
    } \
}

    for (int c = 0; c < 8; ++c) {
        if (t < 512) {
            // ---- producer: T chunk c -> Tc[c&1] ----
            const float* Wp = We2 + (size_t)(c*ACH + aT)*4096 + fT;
            float4 A0={0,0,0,0},A1={0,0,0,0},A2={0,0,0,0},A3={0,0,0,0};
            #pragma unroll 8
            for (int i = 0; i < 64; ++i) {
                float4 w  = *(const float4*)(Wp + (size_t)i*64);
                float4 hv = *(const float4*)&hsT[i][nT];
                A0.x += hv.x*w.x; A0.y += hv.x*w.y; A0.z += hv.x*w.z; A0.w += hv.x*w.w;
                A1.x += hv.y*w.x; A1.y += hv.y*w.y; A1.z += hv.y*w.z; A1.w += hv.y*w.w;
                A2.x += hv.z*w.x; A2.y += hv.z*w.y; A2.z += hv.z*w.z; A2.w += hv.z*w.w;
                A3.x += hv.w*w.x; A3.y += hv.w*w.y; A3.z += hv.w*w.z; A3.w += hv.w*w.w;
            }
            int buf = c & 1;
            *(float4*)&Tc[buf][aT][nT+0][fT] = A0;
            *(float4*)&Tc[buf][aT][nT+1][fT] = A1;
            *(float4*)&Tc[buf][aT][nT+2][fT] = A2;
            *(float4*)&Tc[buf][aT][nT+3][fT] = A3;
        } else {
            {   // ---- consumer: stage he chunk c (consumed next phase) ----
                int le = ct >> 2, a2 = (ct & 3) * 2;
                if (ebase + le < NE)
                    *(float2*)&he_s[c&1][le][a2] =
                        *(const float2*)&he_srt[(size_t)(ebase+le)*64 + c*ACH + a2];
            }
            if (c == 0) {
                // Tb[n][f] = sum_i h[n,i]*be2[i*64+f]  (overlapped w/ producer c0)
                int n = ct >> 5, fp = (ct & 31) * 2;
                float t0 = 0.f, t1 = 0.f;
                #pragma unroll 8
                for (int i = 0; i < 64; ++i) {
                    float hv = hsT[i][n];
                    float2 b = *(const float2*)&be2[(size_t)i*64 + fp];
                    t0 += hv*b.x; t1 += hv*b.y;
                }
                Tb[n][fp]   = t0;
                Tb[n][fp+1] = t1;
            } else {
                CONSUME(c-1);
            }
        }
        __syncthreads();
    }
    if (t >= 512) {
        CONSUME(7);
        // ---- scatter: one atomic add per edge (msg + bias) ----
        if (nl0 >= 0) {
            float4 b = *(const float4*)&Tb[nl0][f4];
            float* ap = agg + (size_t)dt0*64 + f4;
            atomicAdd(ap+0, m0.x+b.x); atomicAdd(ap+1, m0.y+b.y);
            atomicAdd(ap+2, m0.z+b.z); atomicAdd(ap+3, m0.w+b.w);
        }
        if (nl1 >= 0) {
            float4 b = *(const float4*)&Tb[nl1][f4];
            float* ap = agg + (size_t)dt1*64 + f4;
            atomicAdd(ap+0, m1.x+b.x); atomicAdd(ap+1, m1.y+b.y);
            atomicAdd(ap+2, m1.z+b.z); atomicAdd(ap+3, m1.w+b.w);
        }
        if (nl2 >= 0) {
            float4 b = *(const float4*)&Tb[nl2][f4];
            float* ap = agg + (size_t)dt2*64 + f4;
            atomicAdd(ap+0, m2.x+b.x); atomicAdd(ap+1, m2.y+b.y);
            atomicAdd(ap+2, m2.z+b.z); atomicAdd(ap+3, m2.w+b.w);
        }
        if (nl3 >= 0) {
            float4 b = *(const float4*)&Tb[nl3][f4];
            float* ap = agg + (size_t)dt3*64 + f4;
            atomicAdd(ap+0, m3.x+b.x); atomicAdd(ap+1, m3.y+b.y);
            atomicAdd(ap+2, m3.z+b.z); atomicAdd(ap+3, m3.w+b.w);
        }
    }
#undef CONSUME
#undef EDGE_ACC
}

// ---------------- node kernel: m, gi, gh + GRU; thread = (node, gate-col) ----
// 8 nodes / 512 threads / grid 512. Weights streamed from L2 via packed
// W8T[k][g][8] (2 x b128 per k). Zeroes agg for the next conv iteration.
__global__ __launch_bounds__(512) void node_kernel(
    const float* __restrict__ W8T, const float* __restrict__ root,
    const float* __restrict__ conv_b, const float* __restrict__ inv_deg,
    const float* __restrict__ bih, const float* __restrict__ bhh,
    float* __restrict__ h, float* __restrict__ agg)
{
    __shared__ float hs[8][64];
    __shared__ float ms[8][64];
    int t = threadIdx.x;
    int n = t >> 6, g = t & 63;
    int gn = blockIdx.x*8 + n;
    hs[n][g] = h[(size_t)gn*64 + g];
    __syncthreads();
    {   // m = lrelu(agg*inv_deg + h@root + conv_b)
        size_t ix = (size_t)gn*64 + g;
        float v = agg[ix]*inv_deg[gn] + conv_b[g];
        agg[ix] = 0.f;                     // ready for next iteration's conv
        #pragma unroll 8
        for (int k = 0; k < 64; ++k) v += hs[n][k]*root[k*64 + g];
        ms[n][g] = lrelu(v);
    }
    __syncthreads();

    float ir=0.f, iz=0.f, in_=0.f, hr=0.f, hz=0.f, hn=0.f;
    const float* Wp = W8T + (size_t)g*8;
    #pragma unroll 8
    for (int k = 0; k < 64; ++k) {
        float am = ms[n][k], ah = hs[n][k];
        float4 w0 = *(const float4*)(Wp + (size_t)k*512);
        float4 w1 = *(const float4*)(Wp + (size_t)k*512 + 4);
        ir  += am*w0.x; iz += am*w0.y; in_ += am*w0.z;
        hr  += ah*w0.w; hz += ah*w1.x; hn  += ah*w1.y;
    }
    float r  = sigm(ir + bih[g]      + hr + bhh[g]);
    float z  = sigm(iz + bih[64+g]   + hz + bhh[64+g]);
    float nn = tanhf(in_ + bih[128+g] + r*(hn + bhh[128+g]));
    h[(size_t)gn*64 + g] = (1.f - z)*nn + z*hs[n][g];
}

// ---------------- finale: e + softmax-pool + output, one block per graph ----
__device__ __forceinline__ float q_val(const float* lbih, const float* lbhh, int g)
{
    float gi = lbih[g]     + lbhh[g];
    float gg = lbih[128+g] + lbhh[128+g];
    float go = lbih[192+g] + lbhh[192+g];
    return sigm(go)*tanhf(sigm(gi)*tanhf(gg));   // hl0=cl0=q_star0=0
}

__global__ __launch_bounds__(1024) void pool_kernel(
    const float* __restrict__ h, float* __restrict__ e,
    const int* __restrict__ gstart, const int* __restrict__ gend,
    const float* __restrict__ lbih, const float* __restrict__ lbhh,
    const float* __restrict__ Wout, const float* __restrict__ bout,
    float* __restrict__ out)
{
    __shared__ float red[1024];
    __shared__ float qs[64];
    __shared__ float rp[64];
    __shared__ float sval;
    int g = blockIdx.x, t = threadIdx.x;
    int s = gstart[g], en = gend[g];

    if (t < 64) qs[t] = q_val(lbih, lbhh, t);
    __syncthreads();
    int w = t >> 6, f = t & 63;
    for (int n = s + w; n < en; n += 16) {   // e[n] = h[n] . q  (fused e_kernel)
        float p = h[(size_t)n*64 + f]*qs[f];
        #pragma unroll
        for (int off = 32; off; off >>= 1) p += __shfl_xor(p, off);
        if (f == 0) e[n] = p;
    }
    __syncthreads();

    float mx = -1e30f;
    for (int n = s+t; n < en; n += 1024) mx = fmaxf(mx, e[n]);
    red[t] = mx; __syncthreads();
    for (int st = 512; st; st >>= 1) { if (t < st) red[t] = fmaxf(red[t], red[t+st]); __syncthreads(); }
    if (t == 0) sval = red[0];
    __syncthreads();
    float lmx = sval;
    __syncthreads();

    float sm = 0.f;
    for (int n = s+t; n < en; n += 1024) { float a = expf(e[n]-lmx); e[n] = a; sm += a; }
    red[t] = sm; __syncthreads();
    for (int st = 512; st; st >>= 1) { if (t < st) red[t] += red[t+st]; __syncthreads(); }
    if (t == 0) sval = (red[0] > 0.f) ? 1.f/red[0] : 0.f;
    __syncthreads();
    float inv_asum = sval;
    __syncthreads();

    float racc = 0.f;
    for (int n = s+w; n < en; n += 16) racc += e[n]*h[(size_t)n*64 + f];
    red[t] = racc; __syncthreads();
    if (w == 0) {
        float a = 0.f;
        #pragma unroll
        for (int i = 0; i < 16; ++i) a += red[i*64 + f];
        rp[f] = a*inv_asum;
    }
    __syncthreads();

    if (t < 64) {
        float qv = qs[t];
        float p0 = qv*Wout[t*2]   + rp[t]*Wout[(64+t)*2];
        float p1 = qv*Wout[t*2+1] + rp[t]*Wout[(64+t)*2+1];
        #pragma unroll
        for (int off = 32; off; off >>= 1) { p0 += __shfl_xor(p0, off); p1 += __shfl_xor(p1, off); }
        if (t == 0) { out[g*2] = p0 + bout[0]; out[g*2+1] = p1 + bout[1]; }
    }
}

extern "C" void kernel_launch(void* const* d_in, const int* in_sizes, int n_in,
                              void* d_out, int out_size, void* d_ws, size_t ws_size,
                              hipStream_t stream)
{
    const float* x      = (const float*)d_in[0];
    const float* ea     = (const float*)d_in[1];
    const int*   ei     = (const int*)  d_in[2];
    const int*   batch  = (const int*)  d_in[3];
    const float* W0     = (const float*)d_in[4];
    const float* b0     = (const float*)d_in[5];
    const float* We1    = (const float*)d_in[6];
    const float* be1    = (const float*)d_in[7];
    const float* We2    = (const float*)d_in[8];
    const float* be2    = (const float*)d_in[9];
    const float* root   = (const float*)d_in[10];
    const float* conv_b = (const float*)d_in[11];
    const float* Wih    = (const float*)d_in[12];
    const float* Whh    = (const float*)d_in[13];
    const float* bih    = (const float*)d_in[14];
    const float* bhh    = (const float*)d_in[15];
    const float* lbih   = (const float*)d_in[18];
    const float* lbhh   = (const float*)d_in[19];
    const float* Wout   = (const float*)d_in[20];
    const float* bout   = (const float*)d_in[21];
    float* out = (float*)d_out;

    float* W = (float*)d_ws;
    size_t off = 0;
    float* h       = W + off; off += (size_t)NN*64;
    float* he      = W + off; off += (size_t)NE*64;
    float* he_srt  = W + off; off += (size_t)NE*64;
    float* agg     = W + off; off += (size_t)NN*64;
    float* W8T     = W + off; off += 32768;
    float* inv_deg = W + off; off += NN;
    float* e       = W + off; off += NN;
    int*   deg     = (int*)(W + off); off += NN;   // deg+cnt contiguous: one memset
    int*   cnt     = (int*)(W + off); off += NN;
    int*   offs    = (int*)(W + off); off += NN+1;
    int*   srcs    = (int*)(W + off); off += NE;
    int*   dsts    = (int*)(W + off); off += NE;
    int*   perm    = (int*)(W + off); off += NE;
    int*   gstart  = (int*)(W + off); off += BG;
    int*   gend    = (int*)(W + off); off += BG;

    hipMemsetAsync(deg, 0, 2*NN*sizeof(int), stream);
    hipMemsetAsync(agg, 0, (size_t)NN*64*sizeof(float), stream);
    setup_kernel<<<4096, 256, 0, stream>>>(x, ea, ei, W0, b0, We1, be1, Wih, Whh,
                                           W8T, h, he, deg, cnt);
    scan_inv_kernel<<<1, 256, 0, stream>>>(cnt, offs, deg, batch,
                                           inv_deg, gstart, gend);
    scatter_kernel<<<64, 256, 0, stream>>>(ei, offs, cnt, srcs, dsts, perm);
    reorder_kernel<<<4096, 256, 0, stream>>>(he, perm, he_srt);

    for (int it = 0; it < 6; ++it) {
        conv_kernel<<<NN/NT, 1024, 0, stream>>>(h, We2, be2, he_srt,
                                                offs, srcs, dsts, agg);
        node_kernel<<<NN/8, 512, 0, stream>>>(W8T, root, conv_b,
                                              inv_deg, bih, bhh, h, agg);
    }

    pool_kernel<<<BG, 1024, 0, stream>>>(h, e, gstart, gend, lbih, lbhh,
                                         Wout, bout, out);
}

// Round 12
// 579.395 us; speedup vs baseline: 3.1672x; 1.0150x over previous
//
#include <hip/hip_runtime.h>
#include <cstddef>

#define NE 16384
#define NN 4096
#define BG 16
#define NT 16      // nodes per conv tile
#define ACH 8      // a-chunk size (8 chunks of 8 = 64), double-buffered

__device__ __forceinline__ float lrelu(float v){ return v >= 0.f ? v : 0.01f*v; }
__device__ __forceinline__ float sigm(float v){ return 1.f/(1.f + expf(-v)); }

// ---------------- setup: W8T, h0, deg(dst), cnt(src) ----------------
__global__ __launch_bounds__(256) void setup_kernel(
    const float* __restrict__ x, const int* __restrict__ ei,
    const float* __restrict__ W0, const float* __restrict__ b0,
    const float* __restrict__ Wih, const float* __restrict__ Whh,
    float* __restrict__ W8T, float* __restrict__ h,
    int* __restrict__ deg, int* __restrict__ cnt)
{
    int t = blockIdx.x*256 + threadIdx.x;   // grid: 1024x256 = 262144
    {   // h0 = lrelu(x @ W0 + b0)
        int n = t >> 6, f = t & 63;
        float v = b0[f];
        #pragma unroll
        for (int d = 0; d < 3; ++d) v += x[n*3+d]*W0[d*64+f];
        h[t] = lrelu(v);
    }
    if (t < 32768) {    // W8T[k][g][8] = {Wih_r,Wih_z,Wih_n,Whh_r,Whh_z,Whh_n,0,0}
        int k = t >> 9, g = (t >> 3) & 63, j = t & 7;
        float v = 0.f;
        if (j < 3)      v = Wih[(j*64+g)*64 + k];
        else if (j < 6) v = Whh[((j-3)*64+g)*64 + k];
        W8T[t] = v;
    }
    if (t < NE) {
        atomicAdd(&deg[ei[NE + t]], 1);   // in-degree (dst) for mean aggr
        atomicAdd(&cnt[ei[t]], 1);        // out-degree (src) for edge sort
    }
}

// ---------- scan of cnt -> offs  +  inv_deg / per-graph ranges (1 block) ----------
__global__ __launch_bounds__(256) void scan_inv_kernel(
    const int* __restrict__ cnt, int* __restrict__ offs,
    const int* __restrict__ deg, const int* __restrict__ batch,
    float* __restrict__ inv_deg, int* __restrict__ gstart, int* __restrict__ gend)
{
    __shared__ int ps[256];
    int t = threadIdx.x;
    int base = t*16;
    int loc[16];
    int s = 0;
    #pragma unroll
    for (int i = 0; i < 16; ++i) { loc[i] = s; s += cnt[base+i]; }
    ps[t] = s; __syncthreads();
    for (int off = 1; off < 256; off <<= 1) {
        int v = 0;
        if (t >= off) v = ps[t-off];
        __syncthreads();
        if (t >= off) ps[t] += v;
        __syncthreads();
    }
    int pre = (t == 0) ? 0 : ps[t-1];
    #pragma unroll
    for (int i = 0; i < 16; ++i) offs[base+i] = pre + loc[i];
    if (t == 255) offs[NN] = pre + s;

    for (int i = 0; i < 16; ++i) {
        int n = base + i;
        inv_deg[n] = 1.f / fmaxf((float)deg[n], 1.f);
        int b  = batch[n];
        int bp = (n == 0)    ? -1 : batch[n-1];
        int bn = (n == NN-1) ? BG : batch[n+1];
        for (int g = bp+1; g <= b; ++g) gstart[g] = n;
        for (int g = b;   g <  bn; ++g) gend[g]   = n+1;
        if (n == 0)    for (int g = 0;   g < b;  ++g) gend[g]   = 0;
        if (n == NN-1) for (int g = b+1; g < BG; ++g) gstart[g] = NN;
    }
}

// ---------------- scatter: build src-sorted edge arrays ----------------
__global__ __launch_bounds__(256) void scatter_kernel(
    const int* __restrict__ ei, const int* __restrict__ offs,
    int* __restrict__ cnt,  // consumed as cursor via atomicSub
    int* __restrict__ srcs, int* __restrict__ dsts, int* __restrict__ perm)
{
    int e = blockIdx.x*256 + threadIdx.x;
    if (e >= NE) return;
    int s = ei[e], d = ei[NE + e];
    int old = atomicSub(&cnt[s], 1);
    int pos = offs[s] + old - 1;
    srcs[pos] = s; dsts[pos] = d; perm[pos] = e;
}

// ------- reorder + fused edge-MLP layer 1: he_srt[pos] = lrelu(ea[perm]@We1+be1) -------
__global__ __launch_bounds__(256) void reorder_kernel(
    const float* __restrict__ ea, const int* __restrict__ perm,
    const float* __restrict__ We1, const float* __restrict__ be1,
    float* __restrict__ he_srt)
{
    int t = blockIdx.x*256 + threadIdx.x;   // 4096 x 256 = NE*64
    int e = t >> 6, f = t & 63;
    int pe = perm[e];
    float v = be1[f];
    #pragma unroll
    for (int d = 0; d < 4; ++d) v += ea[pe*4+d]*We1[d*64+f];
    he_srt[t] = lrelu(v);
}

// ======== fused conv: [node/GRU prologue for own tile] + R5 conv ========
// Tile x's conv reads ONLY its own 16 nodes' h, and the node/GRU update for
// those nodes is exactly 1024 threads -> node(it-1) runs as a prologue of
// conv(it). Kernel boundary guarantees agg_prev completeness. Node-phase
// registers are dead before the conv loop (unlike R10's mega kernel), so the
// conv phase stays at the proven 64-VGPR/no-spill codegen. ms aliases Tc.
__global__ __launch_bounds__(1024) void conv_fused(
    float* __restrict__ h, const float* __restrict__ We2,
    const float* __restrict__ be2, const float* __restrict__ he_srt,
    const int* __restrict__ offs, const int* __restrict__ srcs,
    const int* __restrict__ dsts, float* __restrict__ agg_cur,
    float* __restrict__ agg_prev,
    const float* __restrict__ W8T, const float* __restrict__ root,
    const float* __restrict__ conv_b, const float* __restrict__ inv_deg,
    const float* __restrict__ bih, const float* __restrict__ bhh,
    int do_node)
{
    __shared__ float hsT[64][NT];          // 4 KB
    __shared__ float Tb [NT][64];          // 4 KB
    __shared__ float Tc [2][ACH][NT][64];  // 64 KB (double-buffered)
    __shared__ float he_s[2][128][ACH];    // 8 KB  -> 80 KB total
    float* ms = &Tc[0][0][0][0];           // node-phase scratch (pre-conv only)
    int t  = threadIdx.x;
    int n0 = blockIdx.x * NT;

    { int n = t >> 6, i = t & 63; hsT[i][n] = h[(size_t)(n0+n)*64 + i]; }
    int ebase = offs[n0];
    int ecnt  = offs[n0+NT] - ebase;
    int eend  = ebase + ecnt;
    __syncthreads();

    // ---------------- node/GRU prologue (updates own tile's h) ----------------
    if (do_node) {
        int n = t >> 6, g = t & 63;        // n wave-uniform
        int gn = n0 + n;
        size_t ix = (size_t)gn*64 + g;
        float v = agg_prev[ix]*inv_deg[gn] + conv_b[g];
        agg_prev[ix] = 0.f;                // ready for iteration it+1's conv
        #pragma unroll 8
        for (int k = 0; k < 64; ++k) v += hsT[k][n]*root[k*64 + g];
        ms[n*64 + g] = lrelu(v);
        __syncthreads();

        float ir=0.f, iz=0.f, in_=0.f, hr=0.f, hz=0.f, hn=0.f;
        const float* Wp = W8T + (size_t)g*8;
        #pragma unroll 8
        for (int k = 0; k < 64; ++k) {
            float am = ms[n*64 + k], ah = hsT[k][n];
            float4 w0 = *(const float4*)(Wp + (size_t)k*512);
            float4 w1 = *(const float4*)(Wp + (size_t)k*512 + 4);
            ir  += am*w0.x; iz += am*w0.y; in_ += am*w0.z;
            hr  += ah*w0.w; hz += ah*w1.x; hn  += ah*w1.y;
        }
        float r  = sigm(ir + bih[g]      + hr + bhh[g]);
        float z  = sigm(iz + bih[64+g]   + hz + bhh[64+g]);
        float nn = tanhf(in_ + bih[128+g] + r*(hn + bhh[128+g]));
        float ho = hsT[g][n];
        float hnew = (1.f - z)*nn + z*ho;
        __syncthreads();                   // all old-h / ms reads done
        hsT[g][n] = hnew;                  // LDS h for this launch's conv
        h[ix] = hnew;                      // global h for next launch / pool
        __syncthreads();
    }

    // ---------------- conv phase (R11 proven code, byte-identical) ----------------
    int aT = t >> 6;               // 0..7  a' within chunk
    int nT = ((t >> 4) & 3) * 4;   // 4 nodes per thread
    int fT = (t & 15) * 4;         // 4 f per thread
    int ct   = t - 512;
    int slot = ct >> 4;            // 0..31 edge slots
    int f4   = (ct & 15) * 4;      // 4 output features per thread
    int nl0=-1,dt0=0,nl1=-1,dt1=0,nl2=-1,dt2=0,nl3=-1,dt3=0;
    float4 m0={0,0,0,0},m1={0,0,0,0},m2={0,0,0,0},m3={0,0,0,0};
    if (t >= 512) {
        if (slot      < ecnt) { nl0 = srcs[ebase+slot]    - n0; dt0 = dsts[ebase+slot];    }
        if (slot + 32 < ecnt) { nl1 = srcs[ebase+slot+32] - n0; dt1 = dsts[ebase+slot+32]; }
        if (slot + 64 < ecnt) { nl2 = srcs[ebase+slot+64] - n0; dt2 = dsts[ebase+slot+64]; }
        if (slot + 96 < ecnt) { nl3 = srcs[ebase+slot+96] - n0; dt3 = dsts[ebase+slot+96]; }
    }

#define EDGE_ACC(mj, nlj, row, buf_) \
    if (nlj >= 0) { \
        float4 hA = *(const float4*)&he_s[buf_][row][0]; \
        float4 hB = *(const float4*)&he_s[buf_][row][4]; \
        float4 t0 = *(const float4*)&Tc[buf_][0][nlj][f4]; \
        float4 t1 = *(const float4*)&Tc[buf_][1][nlj][f4]; \
        float4 t2 = *(const float4*)&Tc[buf_][2][nlj][f4]; \
        float4 t3 = *(const float4*)&Tc[buf_][3][nlj][f4]; \
        float4 t4 = *(const float4*)&Tc[buf_][4][nlj][f4]; \
        float4 t5 = *(const float4*)&Tc[buf_][5][nlj][f4]; \
        float4 t6 = *(const float4*)&Tc[buf_][6][nlj][f4]; \
        float4 t7 = *(const float4*)&Tc[buf_][7][nlj][f4]; \
        mj.x += hA.x*t0.x+hA.y*t1.x+hA.z*t2.x+hA.w*t3.x+hB.x*t4.x+hB.y*t5.x+hB.z*t6.x+hB.w*t7.x; \
        mj.y += hA.x*t0.y+hA.y*t1.y+hA.z*t2.y+hA.w*t3.y+hB.x*t4.y+hB.y*t5.y+hB.z*t6.y+hB.w*t7.y; \
        mj.z += hA.x*t0.z+hA.y*t1.z+hA.z*t2.z+hA.w*t3.z+hB.x*t4.z+hB.y*t5.z+hB.z*t6.z+hB.w*t7.z; \
        mj.w += hA.x*t0.w+hA.y*t1.w+hA.z*t2.w+hA.w*t3.w+hB.x*t4.w+hB.y*t5.w+hB.z*t6.w+hB.w*t7.w; \
    }

#define CONSUME(cm) { \
    int buf_ = (cm) & 1; \
    EDGE_ACC(m0, nl0, (slot),      buf_) \
    EDGE_ACC(m1, nl1, (slot+32),   buf_) \
    EDGE_ACC(m2, nl2, (slot+64),   buf_) \
    EDGE_ACC(m3, nl3, (slot+96),   buf_) \
    for (int e = ebase + 128 + slot; e < eend; e += 32) { \
        int nl = srcs[e] - n0, dtv = dsts[e]; \
        const float* hep = he_srt + (size_t)e*64 + (cm)*ACH; \
        float4 pm = {0,0,0,0}; \
        _Pragma("unroll") \
        for (int a = 0; a < ACH; ++a) { \
            float hv = hep[a]; \
            float4 tv = *(const float4*)&Tc[buf_][a][nl][f4]; \
            pm.x += hv*tv.x; pm.y += hv*tv.y; pm.z += hv*tv.z; pm.w += hv*tv.w; \
        } \
        if ((cm) == 0) { \
            float4 b = *(const float4*)&Tb[nl][f4]; \
            pm.x += b.x; pm.y += b.y; pm.z += b.z; pm.w += b.w; \
        } \
        float* ap = agg_cur + (size_t)dtv*64 + f4; \
        atomicAdd(ap+0, pm.x); atomicAdd(ap+1, pm.y); \
        atomicAdd(ap+2, pm.z); atomicAdd(ap+3, pm.w); \
    } \
}

    for (int c = 0; c < 8; ++c) {
        if (t < 512) {
            // ---- producer: T chunk c -> Tc[c&1] ----
            const float* Wp = We2 + (size_t)(c*ACH + aT)*4096 + fT;
            float4 A0={0,0,0,0},A1={0,0,0,0},A2={0,0,0,0},A3={0,0,0,0};
            #pragma unroll 8
            for (int i = 0; i < 64; ++i) {
                float4 w  = *(const float4*)(Wp + (size_t)i*64);
                float4 hv = *(const float4*)&hsT[i][nT];
                A0.x += hv.x*w.x; A0.y += hv.x*w.y; A0.z += hv.x*w.z; A0.w += hv.x*w.w;
                A1.x += hv.y*w.x; A1.y += hv.y*w.y; A1.z += hv.y*w.z; A1.w += hv.y*w.w;
                A2.x += hv.z*w.x; A2.y += hv.z*w.y; A2.z += hv.z*w.z; A2.w += hv.z*w.w;
                A3.x += hv.w*w.x; A3.y += hv.w*w.y; A3.z += hv.w*w.z; A3.w += hv.w*w.w;
            }
            int buf = c & 1;
            *(float4*)&Tc[buf][aT][nT+0][fT] = A0;
            *(float4*)&Tc[buf][aT][nT+1][fT] = A1;
            *(float4*)&Tc[buf][aT][nT+2][fT] = A2;
            *(float4*)&Tc[buf][aT][nT+3][fT] = A3;
        } else {
            {   // ---- consumer: stage he chunk c (consumed next phase) ----
                int le = ct >> 2, a2 = (ct & 3) * 2;
                if (ebase + le < NE)
                    *(float2*)&he_s[c&1][le][a2] =
                        *(const float2*)&he_srt[(size_t)(ebase+le)*64 + c*ACH + a2];
            }
            if (c == 0) {
                // Tb[n][f] = sum_i h[n,i]*be2[i*64+f]  (overlapped w/ producer c0)
                int n = ct >> 5, fp = (ct & 31) * 2;
                float t0 = 0.f, t1 = 0.f;
                #pragma unroll 8
                for (int i = 0; i < 64; ++i) {
                    float hv = hsT[i][n];
                    float2 b = *(const float2*)&be2[(size_t)i*64 + fp];
                    t0 += hv*b.x; t1 += hv*b.y;
                }
                Tb[n][fp]   = t0;
                Tb[n][fp+1] = t1;
            } else {
                CONSUME(c-1);
            }
        }
        __syncthreads();
    }
    if (t >= 512) {
        CONSUME(7);
        // ---- scatter: one atomic add per edge (msg + bias) ----
        if (nl0 >= 0) {
            float4 b = *(const float4*)&Tb[nl0][f4];
            float* ap = agg_cur + (size_t)dt0*64 + f4;
            atomicAdd(ap+0, m0.x+b.x); atomicAdd(ap+1, m0.y+b.y);
            atomicAdd(ap+2, m0.z+b.z); atomicAdd(ap+3, m0.w+b.w);
        }
        if (nl1 >= 0) {
            float4 b = *(const float4*)&Tb[nl1][f4];
            float* ap = agg_cur + (size_t)dt1*64 + f4;
            atomicAdd(ap+0, m1.x+b.x); atomicAdd(ap+1, m1.y+b.y);
            atomicAdd(ap+2, m1.z+b.z); atomicAdd(ap+3, m1.w+b.w);
        }
        if (nl2 >= 0) {
            float4 b = *(const float4*)&Tb[nl2][f4];
            float* ap = agg_cur + (size_t)dt2*64 + f4;
            atomicAdd(ap+0, m2.x+b.x); atomicAdd(ap+1, m2.y+b.y);
            atomicAdd(ap+2, m2.z+b.z); atomicAdd(ap+3, m2.w+b.w);
        }
        if (nl3 >= 0) {
            float4 b = *(const float4*)&Tb[nl3][f4];
            float* ap = agg_cur + (size_t)dt3*64 + f4;
            atomicAdd(ap+0, m3.x+b.x); atomicAdd(ap+1, m3.y+b.y);
            atomicAdd(ap+2, m3.z+b.z); atomicAdd(ap+3, m3.w+b.w);
        }
    }
#undef CONSUME
#undef EDGE_ACC
}

// ---------------- final node kernel (iteration 5's GRU) ----------------
__global__ __launch_bounds__(512) void node_kernel(
    const float* __restrict__ W8T, const float* __restrict__ root,
    const float* __restrict__ conv_b, const float* __restrict__ inv_deg,
    const float* __restrict__ bih, const float* __restrict__ bhh,
    float* __restrict__ h, float* __restrict__ agg)
{
    __shared__ float hs[8][64];
    __shared__ float ms[8][64];
    int t = threadIdx.x;
    int n = t >> 6, g = t & 63;
    int gn = blockIdx.x*8 + n;
    hs[n][g] = h[(size_t)gn*64 + g];
    __syncthreads();
    {
        size_t ix = (size_t)gn*64 + g;
        float v = agg[ix]*inv_deg[gn] + conv_b[g];
        #pragma unroll 8
        for (int k = 0; k < 64; ++k) v += hs[n][k]*root[k*64 + g];
        ms[n][g] = lrelu(v);
    }
    __syncthreads();

    float ir=0.f, iz=0.f, in_=0.f, hr=0.f, hz=0.f, hn=0.f;
    const float* Wp = W8T + (size_t)g*8;
    #pragma unroll 8
    for (int k = 0; k < 64; ++k) {
        float am = ms[n][k], ah = hs[n][k];
        float4 w0 = *(const float4*)(Wp + (size_t)k*512);
        float4 w1 = *(const float4*)(Wp + (size_t)k*512 + 4);
        ir  += am*w0.x; iz += am*w0.y; in_ += am*w0.z;
        hr  += ah*w0.w; hz += ah*w1.x; hn  += ah*w1.y;
    }
    float r  = sigm(ir + bih[g]      + hr + bhh[g]);
    float z  = sigm(iz + bih[64+g]   + hz + bhh[64+g]);
    float nn = tanhf(in_ + bih[128+g] + r*(hn + bhh[128+g]));
    h[(size_t)gn*64 + g] = (1.f - z)*nn + z*hs[n][g];
}

// ---------------- finale: e + softmax-pool + output, one block per graph ----
__device__ __forceinline__ float q_val(const float* lbih, const float* lbhh, int g)
{
    float gi = lbih[g]     + lbhh[g];
    float gg = lbih[128+g] + lbhh[128+g];
    float go = lbih[192+g] + lbhh[192+g];
    return sigm(go)*tanhf(sigm(gi)*tanhf(gg));   // hl0=cl0=q_star0=0
}

__global__ __launch_bounds__(1024) void pool_kernel(
    const float* __restrict__ h, float* __restrict__ e,
    const int* __restrict__ gstart, const int* __restrict__ gend,
    const float* __restrict__ lbih, const float* __restrict__ lbhh,
    const float* __restrict__ Wout, const float* __restrict__ bout,
    float* __restrict__ out)
{
    __shared__ float red[1024];
    __shared__ float qs[64];
    __shared__ float rp[64];
    __shared__ float sval;
    int g = blockIdx.x, t = threadIdx.x;
    int s = gstart[g], en = gend[g];

    if (t < 64) qs[t] = q_val(lbih, lbhh, t);
    __syncthreads();
    int w = t >> 6, f = t & 63;
    for (int n = s + w; n < en; n += 16) {   // e[n] = h[n] . q
        float p = h[(size_t)n*64 + f]*qs[f];
        #pragma unroll
        for (int off = 32; off; off >>= 1) p += __shfl_xor(p, off);
        if (f == 0) e[n] = p;
    }
    __syncthreads();

    float mx = -1e30f;
    for (int n = s+t; n < en; n += 1024) mx = fmaxf(mx, e[n]);
    red[t] = mx; __syncthreads();
    for (int st = 512; st; st >>= 1) { if (t < st) red[t] = fmaxf(red[t], red[t+st]); __syncthreads(); }
    if (t == 0) sval = red[0];
    __syncthreads();
    float lmx = sval;
    __syncthreads();

    float sm = 0.f;
    for (int n = s+t; n < en; n += 1024) { float a = expf(e[n]-lmx); e[n] = a; sm += a; }
    red[t] = sm; __syncthreads();
    for (int st = 512; st; st >>= 1) { if (t < st) red[t] += red[t+st]; __syncthreads(); }
    if (t == 0) sval = (red[0] > 0.f) ? 1.f/red[0] : 0.f;
    __syncthreads();
    float inv_asum = sval;
    __syncthreads();

    float racc = 0.f;
    for (int n = s+w; n < en; n += 16) racc += e[n]*h[(size_t)n*64 + f];
    red[t] = racc; __syncthreads();
    if (w == 0) {
        float a = 0.f;
        #pragma unroll
        for (int i = 0; i < 16; ++i) a += red[i*64 + f];
        rp[f] = a*inv_asum;
    }
    __syncthreads();

    if (t < 64) {
        float qv = qs[t];
        float p0 = qv*Wout[t*2]   + rp[t]*Wout[(64+t)*2];
        float p1 = qv*Wout[t*2+1] + rp[t]*Wout[(64+t)*2+1];
        #pragma unroll
        for (int off = 32; off; off >>= 1) { p0 += __shfl_xor(p0, off); p1 += __shfl_xor(p1, off); }
        if (t == 0) { out[g*2] = p0 + bout[0]; out[g*2+1] = p1 + bout[1]; }
    }
}

extern "C" void kernel_launch(void* const* d_in, const int* in_sizes, int n_in,
                              void* d_out, int out_size, void* d_ws, size_t ws_size,
                              hipStream_t stream)
{
    const float* x      = (const float*)d_in[0];
    const float* ea     = (const float*)d_in[1];
    const int*   ei     = (const int*)  d_in[2];
    const int*   batch  = (const int*)  d_in[3];
    const float* W0     = (const float*)d_in[4];
    const float* b0     = (const float*)d_in[5];
    const float* We1    = (const float*)d_in[6];
    const float* be1    = (const float*)d_in[7];
    const float* We2    = (const float*)d_in[8];
    const float* be2    = (const float*)d_in[9];
    const float* root   = (const float*)d_in[10];
    const float* conv_b = (const float*)d_in[11];
    const float* Wih    = (const float*)d_in[12];
    const float* Whh    = (const float*)d_in[13];
    const float* bih    = (const float*)d_in[14];
    const float* bhh    = (const float*)d_in[15];
    const float* lbih   = (const float*)d_in[18];
    const float* lbhh   = (const float*)d_in[19];
    const float* Wout   = (const float*)d_in[20];
    const float* bout   = (const float*)d_in[21];
    float* out = (float*)d_out;

    float* W = (float*)d_ws;
    size_t off = 0;
    float* h       = W + off; off += (size_t)NN*64;
    float* he_srt  = W + off; off += (size_t)NE*64;
    float* agg     = W + off; off += (size_t)2*NN*64;   // dbuf by it&1
    float* W8T     = W + off; off += 32768;
    float* inv_deg = W + off; off += NN;
    float* e       = W + off; off += NN;
    int*   deg     = (int*)(W + off); off += NN;   // deg+cnt contiguous: one memset
    int*   cnt     = (int*)(W + off); off += NN;
    int*   offs    = (int*)(W + off); off += NN+1;
    int*   srcs    = (int*)(W + off); off += NE;
    int*   dsts    = (int*)(W + off); off += NE;
    int*   perm    = (int*)(W + off); off += NE;
    int*   gstart  = (int*)(W + off); off += BG;
    int*   gend    = (int*)(W + off); off += BG;

    hipMemsetAsync(deg, 0, 2*NN*sizeof(int), stream);
    hipMemsetAsync(agg, 0, (size_t)2*NN*64*sizeof(float), stream);
    setup_kernel<<<1024, 256, 0, stream>>>(x, ei, W0, b0, Wih, Whh,
                                           W8T, h, deg, cnt);
    scan_inv_kernel<<<1, 256, 0, stream>>>(cnt, offs, deg, batch,
                                           inv_deg, gstart, gend);
    scatter_kernel<<<64, 256, 0, stream>>>(ei, offs, cnt, srcs, dsts, perm);
    reorder_kernel<<<4096, 256, 0, stream>>>(ea, perm, We1, be1, he_srt);

    for (int it = 0; it < 6; ++it) {
        float* agg_cur  = agg + (size_t)(it & 1) * NN * 64;
        float* agg_prev = agg + (size_t)((it + 1) & 1) * NN * 64;
        conv_fused<<<NN/NT, 1024, 0, stream>>>(h, We2, be2, he_srt,
                                               offs, srcs, dsts, agg_cur, agg_prev,
                                               W8T, root, conv_b, inv_deg,
                                               bih, bhh, it > 0 ? 1 : 0);
    }
    // final GRU consumes agg of iteration 5 (buffer 5&1 = 1)
    node_kernel<<<NN/8, 512, 0, stream>>>(W8T, root, conv_b, inv_deg,
                                          bih, bhh, h, agg + (size_t)NN*64);

    pool_kernel<<<BG, 1024, 0, stream>>>(h, e, gstart, gend, lbih, lbhh,
                                         Wout, bout, out);
}

// Round 13
// 567.426 us; speedup vs baseline: 3.2340x; 1.0211x over previous
//
#include <hip/hip_runtime.h>
#include <cstddef>

#define NE 16384
#define NN 4096
#define BG 16
#define NT 16      // nodes per conv tile
#define ACH 8      // a-chunk size (8 chunks of 8 = 64), double-buffered

__device__ __forceinline__ float lrelu(float v){ return v >= 0.f ? v : 0.01f*v; }
__device__ __forceinline__ float sigm(float v){ return 1.f/(1.f + expf(-v)); }

// ---------------- setup: W8T, h0, deg(dst), cnt(src) ----------------
__global__ __launch_bounds__(256) void setup_kernel(
    const float* __restrict__ x, const int* __restrict__ ei,
    const float* __restrict__ W0, const float* __restrict__ b0,
    const float* __restrict__ Wih, const float* __restrict__ Whh,
    float* __restrict__ W8T, float* __restrict__ h,
    int* __restrict__ deg, int* __restrict__ cnt)
{
    int t = blockIdx.x*256 + threadIdx.x;   // grid: 1024x256 = 262144
    {   // h0 = lrelu(x @ W0 + b0)
        int n = t >> 6, f = t & 63;
        float v = b0[f];
        #pragma unroll
        for (int d = 0; d < 3; ++d) v += x[n*3+d]*W0[d*64+f];
        h[t] = lrelu(v);
    }
    if (t < 32768) {    // W8T[k][g][8] = {Wih_r,Wih_z,Wih_n,Whh_r,Whh_z,Whh_n,0,0}
        int k = t >> 9, g = (t >> 3) & 63, j = t & 7;
        float v = 0.f;
        if (j < 3)      v = Wih[(j*64+g)*64 + k];
        else if (j < 6) v = Whh[((j-3)*64+g)*64 + k];
        W8T[t] = v;
    }
    if (t < NE) {
        atomicAdd(&deg[ei[NE + t]], 1);   // in-degree (dst) for mean aggr
        atomicAdd(&cnt[ei[t]], 1);        // out-degree (src) for edge sort
    }
}

// ---------- scan of cnt -> offs  +  inv_deg / per-graph ranges (1 block) ----------
__global__ __launch_bounds__(256) void scan_inv_kernel(
    const int* __restrict__ cnt, int* __restrict__ offs,
    const int* __restrict__ deg, const int* __restrict__ batch,
    float* __restrict__ inv_deg, int* __restrict__ gstart, int* __restrict__ gend)
{
    __shared__ int ps[256];
    int t = threadIdx.x;
    int base = t*16;
    int loc[16];
    int s = 0;
    #pragma unroll
    for (int i = 0; i < 16; ++i) { loc[i] = s; s += cnt[base+i]; }
    ps[t] = s; __syncthreads();
    for (int off = 1; off < 256; off <<= 1) {
        int v = 0;
        if (t >= off) v = ps[t-off];
        __syncthreads();
        if (t >= off) ps[t] += v;
        __syncthreads();
    }
    int pre = (t == 0) ? 0 : ps[t-1];
    #pragma unroll
    for (int i = 0; i < 16; ++i) offs[base+i] = pre + loc[i];
    if (t == 255) offs[NN] = pre + s;

    for (int i = 0; i < 16; ++i) {
        int n = base + i;
        inv_deg[n] = 1.f / fmaxf((float)deg[n], 1.f);
        int b  = batch[n];
        int bp = (n == 0)    ? -1 : batch[n-1];
        int bn = (n == NN-1) ? BG : batch[n+1];
        for (int g = bp+1; g <= b; ++g) gstart[g] = n;
        for (int g = b;   g <  bn; ++g) gend[g]   = n+1;
        if (n == 0)    for (int g = 0;   g < b;  ++g) gend[g]   = 0;
        if (n == NN-1) for (int g = b+1; g < BG; ++g) gstart[g] = NN;
    }
}

// ---------------- scatter: build src-sorted edge arrays ----------------
__global__ __launch_bounds__(256) void scatter_kernel(
    const int* __restrict__ ei, const int* __restrict__ offs,
    int* __restrict__ cnt,  // consumed as cursor via atomicSub
    int* __restrict__ srcs, int* __restrict__ dsts, int* __restrict__ perm)
{
    int e = blockIdx.x*256 + threadIdx.x;
    if (e >= NE) return;
    int s = ei[e], d = ei[NE + e];
    int old = atomicSub(&cnt[s], 1);
    int pos = offs[s] + old - 1;
    srcs[pos] = s; dsts[pos] = d; perm[pos] = e;
}

// ------- reorder + fused edge-MLP layer 1: he_srt[pos] = lrelu(ea[perm]@We1+be1) -------
__global__ __launch_bounds__(256) void reorder_kernel(
    const float* __restrict__ ea, const int* __restrict__ perm,
    const float* __restrict__ We1, const float* __restrict__ be1,
    float* __restrict__ he_srt)
{
    int t = blockIdx.x*256 + threadIdx.x;   // 4096 x 256 = NE*64
    int e = t >> 6, f = t & 63;
    int pe = perm[e];
    float v = be1[f];
    #pragma unroll
    for (int d = 0; d < 4; ++d) v += ea[pe*4+d]*We1[d*64+f];
    he_srt[t] = lrelu(v);
}

// ---------------- fused conv: producer/consumer wave role-split ----------------
// R5 byte-exact (best-measured config: 557.95 us total; 64 VGPR, no spill).
// R6-R12 lesson: every restructure of this kernel either spills at the
// immovable 64-VGPR cap (h-in-regs, mega, min-waves hints) or trades one
// pipe for another at par (tile/block reshapes). Do not touch.
__global__ __launch_bounds__(1024) void conv_kernel(
    const float* __restrict__ h, const float* __restrict__ We2,
    const float* __restrict__ be2, const float* __restrict__ he_srt,
    const int* __restrict__ offs, const int* __restrict__ srcs,
    const int* __restrict__ dsts, float* __restrict__ agg)
{
    __shared__ float hsT[64][NT];          // 4 KB
    __shared__ float Tb [NT][64];          // 4 KB
    __shared__ float Tc [2][ACH][NT][64];  // 64 KB (double-buffered)
    __shared__ float he_s[2][128][ACH];    // 8 KB  (double-buffered) -> 80 KB
    int t  = threadIdx.x;
    int n0 = blockIdx.x * NT;

    { int n = t >> 6, i = t & 63; hsT[i][n] = h[(size_t)(n0+n)*64 + i]; }
    int ebase = offs[n0];
    int ecnt  = offs[n0+NT] - ebase;
    int eend  = ebase + ecnt;
    __syncthreads();

    // producer mapping (t < 512)
    int aT = t >> 6;               // 0..7  a' within chunk
    int nT = ((t >> 4) & 3) * 4;   // 4 nodes per thread
    int fT = (t & 15) * 4;         // 4 f per thread
    // consumer mapping + persistent state (t >= 512)
    int ct   = t - 512;
    int slot = ct >> 4;            // 0..31 edge slots
    int f4   = (ct & 15) * 4;      // 4 output features per thread
    int nl0=-1,dt0=0,nl1=-1,dt1=0,nl2=-1,dt2=0,nl3=-1,dt3=0;
    float4 m0={0,0,0,0},m1={0,0,0,0},m2={0,0,0,0},m3={0,0,0,0};
    if (t >= 512) {
        if (slot      < ecnt) { nl0 = srcs[ebase+slot]    - n0; dt0 = dsts[ebase+slot];    }
        if (slot + 32 < ecnt) { nl1 = srcs[ebase+slot+32] - n0; dt1 = dsts[ebase+slot+32]; }
        if (slot + 64 < ecnt) { nl2 = srcs[ebase+slot+64] - n0; dt2 = dsts[ebase+slot+64]; }
        if (slot + 96 < ecnt) { nl3 = srcs[ebase+slot+96] - n0; dt3 = dsts[ebase+slot+96]; }
    }

#define EDGE_ACC(mj, nlj, row, buf_) \
    if (nlj >= 0) { \
        float4 hA = *(const float4*)&he_s[buf_][row][0]; \
        float4 hB = *(const float4*)&he_s[buf_][row][4]; \
        float4 t0 = *(const float4*)&Tc[buf_][0][nlj][f4]; \
        float4 t1 = *(const float4*)&Tc[buf_][1][nlj][f4]; \
        float4 t2 = *(const float4*)&Tc[buf_][2][nlj][f4]; \
        float4 t3 = *(const float4*)&Tc[buf_][3][nlj][f4]; \
        float4 t4 = *(const float4*)&Tc[buf_][4][nlj][f4]; \
        float4 t5 = *(const float4*)&Tc[buf_][5][nlj][f4]; \
        float4 t6 = *(const float4*)&Tc[buf_][6][nlj][f4]; \
        float4 t7 = *(const float4*)&Tc[buf_][7][nlj][f4]; \
        mj.x += hA.x*t0.x+hA.y*t1.x+hA.z*t2.x+hA.w*t3.x+hB.x*t4.x+hB.y*t5.x+hB.z*t6.x+hB.w*t7.x; \
        mj.y += hA.x*t0.y+hA.y*t1.y+hA.z*t2.y+hA.w*t3.y+hB.x*t4.y+hB.y*t5.y+hB.z*t6.y+hB.w*t7.y; \
        mj.z += hA.x*t0.z+hA.y*t1.z+hA.z*t2.z+hA.w*t3.z+hB.x*t4.z+hB.y*t5.z+hB.z*t6.z+hB.w*t7.z; \
        mj.w += hA.x*t0.w+hA.y*t1.w+hA.z*t2.w+hA.w*t3.w+hB.x*t4.w+hB.y*t5.w+hB.z*t6.w+hB.w*t7.w; \
    }

#define CONSUME(cm) { \
    int buf_ = (cm) & 1; \
    EDGE_ACC(m0, nl0, (slot),      buf_) \
    EDGE_ACC(m1, nl1, (slot+32),   buf_) \
    EDGE_ACC(m2, nl2, (slot+64),   buf_) \
    EDGE_ACC(m3, nl3, (slot+96),   buf_) \
    for (int e = ebase + 128 + slot; e < eend; e += 32) { \
        int nl = srcs[e] - n0, dtv = dsts[e]; \
        const float* hep = he_srt + (size_t)e*64 + (cm)*ACH; \
        float4 pm = {0,0,0,0}; \
        _Pragma("unroll") \
        for (int a = 0; a < ACH; ++a) { \
            float hv = hep[a]; \
            float4 tv = *(const float4*)&Tc[buf_][a][nl][f4]; \
            pm.x += hv*tv.x; pm.y += hv*tv.y; pm.z += hv*tv.z; pm.w += hv*tv.w; \
        } \
        if ((cm) == 0) { \
            float4 b = *(const float4*)&Tb[nl][f4]; \
            pm.x += b.x; pm.y += b.y; pm.z += b.z; pm.w += b.w; \
        } \
        float* ap = agg + (size_t)dtv*64 + f4; \
        atomicAdd(ap+0, pm.x); atomicAdd(ap+1, pm.y); \
        atomicAdd(ap+2, pm.z); atomicAdd(ap+3, pm.w); \
    } \
}

    for (int c = 0; c < 8; ++c) {
        if (t < 512) {
            // ---- producer: T chunk c -> Tc[c&1] ----
            const float* Wp = We2 + (size_t)(c*ACH + aT)*4096 + fT;
            float4 A0={0,0,0,0},A1={0,0,0,0},A2={0,0,0,0},A3={0,0,0,0};
            #pragma unroll 8
            for (int i = 0; i < 64; ++i) {
                float4 w  = *(const float4*)(Wp + (size_t)i*64);
                float4 hv = *(const float4*)&hsT[i][nT];
                A0.x += hv.x*w.x; A0.y += hv.x*w.y; A0.z += hv.x*w.z; A0.w += hv.x*w.w;
                A1.x += hv.y*w.x; A1.y += hv.y*w.y; A1.z += hv.y*w.z; A1.w += hv.y*w.w;
                A2.x += hv.z*w.x; A2.y += hv.z*w.y; A2.z += hv.z*w.z; A2.w += hv.z*w.w;
                A3.x += hv.w*w.x; A3.y += hv.w*w.y; A3.z += hv.w*w.z; A3.w += hv.w*w.w;
            }
            int buf = c & 1;
            *(float4*)&Tc[buf][aT][nT+0][fT] = A0;
            *(float4*)&Tc[buf][aT][nT+1][fT] = A1;
            *(float4*)&Tc[buf][aT][nT+2][fT] = A2;
            *(float4*)&Tc[buf][aT][nT+3][fT] = A3;
            if (c == 0) {   // Tb[n][f] = sum_i h[n,i]*be2[i*64+f]  (2 vals/thread)
                #pragma unroll
                for (int r = 0; r < 2; ++r) {
                    int idx = t + r*512;
                    int n = idx >> 6, f = idx & 63;
                    float acc = 0.f;
                    #pragma unroll 8
                    for (int i = 0; i < 64; ++i) acc += hsT[i][n]*be2[i*64+f];
                    Tb[n][f] = acc;
                }
            }
        } else {
            {   // ---- consumer: stage he chunk c (consumed next phase) ----
                int le = ct >> 2, a2 = (ct & 3) * 2;
                if (ebase + le < NE)
                    *(float2*)&he_s[c&1][le][a2] =
                        *(const float2*)&he_srt[(size_t)(ebase+le)*64 + c*ACH + a2];
            }
            if (c >= 1) CONSUME(c-1);
        }
        __syncthreads();
    }
    if (t >= 512) {
        CONSUME(7);
        // ---- scatter: one atomic add per edge (msg + bias) ----
        if (nl0 >= 0) {
            float4 b = *(const float4*)&Tb[nl0][f4];
            float* ap = agg + (size_t)dt0*64 + f4;
            atomicAdd(ap+0, m0.x+b.x); atomicAdd(ap+1, m0.y+b.y);
            atomicAdd(ap+2, m0.z+b.z); atomicAdd(ap+3, m0.w+b.w);
        }
        if (nl1 >= 0) {
            float4 b = *(const float4*)&Tb[nl1][f4];
            float* ap = agg + (size_t)dt1*64 + f4;
            atomicAdd(ap+0, m1.x+b.x); atomicAdd(ap+1, m1.y+b.y);
            atomicAdd(ap+2, m1.z+b.z); atomicAdd(ap+3, m1.w+b.w);
        }
        if (nl2 >= 0) {
            float4 b = *(const float4*)&Tb[nl2][f4];
            float* ap = agg + (size_t)dt2*64 + f4;
            atomicAdd(ap+0, m2.x+b.x); atomicAdd(ap+1, m2.y+b.y);
            atomicAdd(ap+2, m2.z+b.z); atomicAdd(ap+3, m2.w+b.w);
        }
        if (nl3 >= 0) {
            float4 b = *(const float4*)&Tb[nl3][f4];
            float* ap = agg + (size_t)dt3*64 + f4;
            atomicAdd(ap+0, m3.x+b.x); atomicAdd(ap+1, m3.y+b.y);
            atomicAdd(ap+2, m3.z+b.z); atomicAdd(ap+3, m3.w+b.w);
        }
    }
#undef CONSUME
#undef EDGE_ACC
}

// ---------------- node kernel: m, gi, gh + GRU; thread = (node, gate-col) ----
// R5 byte-exact. 8 nodes / 512 threads / grid 512. Zeroes agg for next conv.
__global__ __launch_bounds__(512) void node_kernel(
    const float* __restrict__ W8T, const float* __restrict__ root,
    const float* __restrict__ conv_b, const float* __restrict__ inv_deg,
    const float* __restrict__ bih, const float* __restrict__ bhh,
    float* __restrict__ h, float* __restrict__ agg)
{
    __shared__ float hs[8][64];
    __shared__ float ms[8][64];
    int t = threadIdx.x;
    int n = t >> 6, g = t & 63;
    int gn = blockIdx.x*8 + n;
    hs[n][g] = h[(size_t)gn*64 + g];
    __syncthreads();
    {   // m = lrelu(agg*inv_deg + h@root + conv_b)
        size_t ix = (size_t)gn*64 + g;
        float v = agg[ix]*inv_deg[gn] + conv_b[g];
        agg[ix] = 0.f;                     // ready for next iteration's conv
        #pragma unroll 8
        for (int k = 0; k < 64; ++k) v += hs[n][k]*root[k*64 + g];
        ms[n][g] = lrelu(v);
    }
    __syncthreads();

    float ir=0.f, iz=0.f, in_=0.f, hr=0.f, hz=0.f, hn=0.f;
    const float* Wp = W8T + (size_t)g*8;
    #pragma unroll 8
    for (int k = 0; k < 64; ++k) {
        float am = ms[n][k], ah = hs[n][k];
        float4 w0 = *(const float4*)(Wp + (size_t)k*512);
        float4 w1 = *(const float4*)(Wp + (size_t)k*512 + 4);
        ir  += am*w0.x; iz += am*w0.y; in_ += am*w0.z;
        hr  += ah*w0.w; hz += ah*w1.x; hn  += ah*w1.y;
    }
    float r  = sigm(ir + bih[g]      + hr + bhh[g]);
    float z  = sigm(iz + bih[64+g]   + hz + bhh[64+g]);
    float nn = tanhf(in_ + bih[128+g] + r*(hn + bhh[128+g]));
    h[(size_t)gn*64 + g] = (1.f - z)*nn + z*hs[n][g];
}

// ---------------- finale: e + softmax-pool + output, one block per graph ----
__device__ __forceinline__ float q_val(const float* lbih, const float* lbhh, int g)
{
    float gi = lbih[g]     + lbhh[g];
    float gg = lbih[128+g] + lbhh[128+g];
    float go = lbih[192+g] + lbhh[192+g];
    return sigm(go)*tanhf(sigm(gi)*tanhf(gg));   // hl0=cl0=q_star0=0
}

__global__ __launch_bounds__(1024) void pool_kernel(
    const float* __restrict__ h, float* __restrict__ e,
    const int* __restrict__ gstart, const int* __restrict__ gend,
    const float* __restrict__ lbih, const float* __restrict__ lbhh,
    const float* __restrict__ Wout, const float* __restrict__ bout,
    float* __restrict__ out)
{
    __shared__ float red[1024];
    __shared__ float qs[64];
    __shared__ float rp[64];
    __shared__ float sval;
    int g = blockIdx.x, t = threadIdx.x;
    int s = gstart[g], en = gend[g];

    if (t < 64) qs[t] = q_val(lbih, lbhh, t);
    __syncthreads();
    int w = t >> 6, f = t & 63;
    for (int n = s + w; n < en; n += 16) {   // e[n] = h[n] . q  (fused e_kernel)
        float p = h[(size_t)n*64 + f]*qs[f];
        #pragma unroll
        for (int off = 32; off; off >>= 1) p += __shfl_xor(p, off);
        if (f == 0) e[n] = p;
    }
    __syncthreads();

    float mx = -1e30f;
    for (int n = s+t; n < en; n += 1024) mx = fmaxf(mx, e[n]);
    red[t] = mx; __syncthreads();
    for (int st = 512; st; st >>= 1) { if (t < st) red[t] = fmaxf(red[t], red[t+st]); __syncthreads(); }
    if (t == 0) sval = red[0];
    __syncthreads();
    float lmx = sval;
    __syncthreads();

    float sm = 0.f;
    for (int n = s+t; n < en; n += 1024) { float a = expf(e[n]-lmx); e[n] = a; sm += a; }
    red[t] = sm; __syncthreads();
    for (int st = 512; st; st >>= 1) { if (t < st) red[t] += red[t+st]; __syncthreads(); }
    if (t == 0) sval = (red[0] > 0.f) ? 1.f/red[0] : 0.f;
    __syncthreads();
    float inv_asum = sval;
    __syncthreads();

    float racc = 0.f;
    for (int n = s+w; n < en; n += 16) racc += e[n]*h[(size_t)n*64 + f];
    red[t] = racc; __syncthreads();
    if (w == 0) {
        float a = 0.f;
        #pragma unroll
        for (int i = 0; i < 16; ++i) a += red[i*64 + f];
        rp[f] = a*inv_asum;
    }
    __syncthreads();

    if (t < 64) {
        float qv = qs[t];
        float p0 = qv*Wout[t*2]   + rp[t]*Wout[(64+t)*2];
        float p1 = qv*Wout[t*2+1] + rp[t]*Wout[(64+t)*2+1];
        #pragma unroll
        for (int off = 32; off; off >>= 1) { p0 += __shfl_xor(p0, off); p1 += __shfl_xor(p1, off); }
        if (t == 0) { out[g*2] = p0 + bout[0]; out[g*2+1] = p1 + bout[1]; }
    }
}

extern "C" void kernel_launch(void* const* d_in, const int* in_sizes, int n_in,
                              void* d_out, int out_size, void* d_ws, size_t ws_size,
                              hipStream_t stream)
{
    const float* x      = (const float*)d_in[0];
    const float* ea     = (const float*)d_in[1];
    const int*   ei     = (const int*)  d_in[2];
    const int*   batch  = (const int*)  d_in[3];
    const float* W0     = (const float*)d_in[4];
    const float* b0     = (const float*)d_in[5];
    const float* We1    = (const float*)d_in[6];
    const float* be1    = (const float*)d_in[7];
    const float* We2    = (const float*)d_in[8];
    const float* be2    = (const float*)d_in[9];
    const float* root   = (const float*)d_in[10];
    const float* conv_b = (const float*)d_in[11];
    const float* Wih    = (const float*)d_in[12];
    const float* Whh    = (const float*)d_in[13];
    const float* bih    = (const float*)d_in[14];
    const float* bhh    = (const float*)d_in[15];
    const float* lbih   = (const float*)d_in[18];
    const float* lbhh   = (const float*)d_in[19];
    const float* Wout   = (const float*)d_in[20];
    const float* bout   = (const float*)d_in[21];
    float* out = (float*)d_out;

    float* W = (float*)d_ws;
    size_t off = 0;
    float* h       = W + off; off += (size_t)NN*64;
    float* he_srt  = W + off; off += (size_t)NE*64;
    float* agg     = W + off; off += (size_t)NN*64;
    float* W8T     = W + off; off += 32768;
    float* inv_deg = W + off; off += NN;
    float* e       = W + off; off += NN;
    int*   deg     = (int*)(W + off); off += NN;   // deg+cnt contiguous: one memset
    int*   cnt     = (int*)(W + off); off += NN;
    int*   offs    = (int*)(W + off); off += NN+1;
    int*   srcs    = (int*)(W + off); off += NE;
    int*   dsts    = (int*)(W + off); off += NE;
    int*   perm    = (int*)(W + off); off += NE;
    int*   gstart  = (int*)(W + off); off += BG;
    int*   gend    = (int*)(W + off); off += BG;

    hipMemsetAsync(deg, 0, 2*NN*sizeof(int), stream);
    hipMemsetAsync(agg, 0, (size_t)NN*64*sizeof(float), stream);
    setup_kernel<<<1024, 256, 0, stream>>>(x, ei, W0, b0, Wih, Whh,
                                           W8T, h, deg, cnt);
    scan_inv_kernel<<<1, 256, 0, stream>>>(cnt, offs, deg, batch,
                                           inv_deg, gstart, gend);
    scatter_kernel<<<64, 256, 0, stream>>>(ei, offs, cnt, srcs, dsts, perm);
    reorder_kernel<<<4096, 256, 0, stream>>>(ea, perm, We1, be1, he_srt);

    for (int it = 0; it < 6; ++it) {
        conv_kernel<<<NN/NT, 1024, 0, stream>>>(h, We2, be2, he_srt,
                                                offs, srcs, dsts, agg);
        node_kernel<<<NN/8, 512, 0, stream>>>(W8T, root, conv_b,
                                              inv_deg, bih, bhh, h, agg);
    }

    pool_kernel<<<BG, 1024, 0, stream>>>(h, e, gstart, gend, lbih, lbhh,
                                         Wout, bout, out);
}